// Round 2
// baseline (3769.548 us; speedup 1.0000x reference)
//
#include <hip/hip_runtime.h>

#define NB 4
#define CCH 256
#define HW 4096
#define CPG 32
#define EPSV 1e-5f

// ---------------- GroupNorm stats: one block per (n, g), 32*4096=131072 elems ----------------
__global__ __launch_bounds__(256) void gn_stats(const float* __restrict__ x, float* __restrict__ stats) {
    int grp = blockIdx.x;  // n*8+g ; group channels are contiguous
    const float4* base = (const float4*)(x + (size_t)grp * CPG * HW);  // 32768 float4
    int t = threadIdx.x;
    float s = 0.f, sq = 0.f;
    for (int i = t; i < 32768; i += 256) {
        float4 v = base[i];
        s += v.x + v.y + v.z + v.w;
        sq += v.x * v.x + v.y * v.y + v.z * v.z + v.w * v.w;
    }
    __shared__ float rs[256], rq[256];
    rs[t] = s; rq[t] = sq;
    __syncthreads();
    for (int o = 128; o > 0; o >>= 1) {
        if (t < o) { rs[t] += rs[t + o]; rq[t] += rq[t + o]; }
        __syncthreads();
    }
    if (t == 0) {
        float mean = rs[0] * (1.f / 131072.f);
        float var = rq[0] * (1.f / 131072.f) - mean * mean;
        stats[grp] = mean;
        stats[32 + grp] = rsqrtf(var + EPSV);
    }
}

// ---------------- GroupNorm apply -> fp32 x_norm ----------------
__global__ __launch_bounds__(256) void gn_apply(const float* __restrict__ x, const float* __restrict__ w,
                                                const float* __restrict__ b, const float* __restrict__ stats,
                                                float* __restrict__ xn) {
    int idx = blockIdx.x * 256 + threadIdx.x;  // one per 4 elements
    int base = idx * 4;
    int c = (base >> 12) & 255;
    int n = base >> 20;
    int grp = n * 8 + (c >> 5);
    float mean = stats[grp], rstd = stats[32 + grp];
    float a = rstd * w[c];
    float bb = b[c] - mean * a;
    float4 v = *(const float4*)(x + base);
    float4 o;
    o.x = v.x * a + bb;
    o.y = v.y * a + bb;
    o.z = v.z * a + bb;
    o.w = v.w * a + bb;
    *(float4*)(xn + base) = o;
}

// ---------------- QKV GEMM: qkv[n][o][p] = b[o] + sum_c W[o][c]*xn[n][c][p] ----------------
// grid (HW/64, 768/64, N), block 256. Tile 64o x 64p, 16 outputs/thread.
__global__ __launch_bounds__(256) void qkv_gemm(const float* __restrict__ xn, const float* __restrict__ wq,
                                                const float* __restrict__ bq, float* __restrict__ qkv) {
    __shared__ float Xs[16][64];
    __shared__ float Ws[64][16];
    int t = threadIdx.x;
    int p0 = blockIdx.x * 64;
    int o0 = blockIdx.y * 64;
    int n = blockIdx.z;
    int pl = t & 63, og = t >> 6;
    float acc[16];
#pragma unroll
    for (int i = 0; i < 16; i++) acc[i] = 0.f;
    const float* xbase = xn + (size_t)n * CCH * HW + p0;
    for (int cs = 0; cs < 256; cs += 16) {
        {
            int idx = t * 4; int row = idx >> 6; int col = idx & 63;
            *(float4*)&Xs[row][col] = *(const float4*)(xbase + (size_t)(cs + row) * HW + col);
        }
        {
            int idx = t * 4; int ol = idx >> 4; int cc = idx & 15;
            float4 v = *(const float4*)(wq + (size_t)(o0 + ol) * 256 + cs + cc);
            Ws[ol][cc] = v.x;
            Ws[ol][cc + 1] = v.y;
            Ws[ol][cc + 2] = v.z;
            Ws[ol][cc + 3] = v.w;
        }
        __syncthreads();
#pragma unroll
        for (int cc = 0; cc < 16; cc++) {
            float xv = Xs[cc][pl];
#pragma unroll
            for (int i = 0; i < 16; i++) acc[i] += Ws[og * 16 + i][cc] * xv;
        }
        __syncthreads();
    }
    float* obase = qkv + (size_t)n * 768 * HW + (size_t)o0 * HW + p0;
#pragma unroll
    for (int i = 0; i < 16; i++) {
        int o = og * 16 + i;
        obase[(size_t)o * HW + pl] = acc[i] + bq[o0 + o];
    }
}

// ---------------- Flash attention: grid (64 q-tiles, N*NH), block 256 ----------------
// qkv layout [n][768][HW]: q at o=h*64+d, k at 256+h*64+d, v at 512+h*64+d.
__global__ __launch_bounds__(256) void flash_attn(const float* __restrict__ qkv, float* __restrict__ attn) {
    __shared__ float Qs[64][64];     // Qs[d][r]
    __shared__ float KS[64][65];     // K tile, reused as score buffer Sc[r][j]
    __shared__ float Vs[64][65];     // Vs[d][j]
    __shared__ float mrow[64], lrow[64], arow[64];
    int t = threadIdx.x;
    int q0 = blockIdx.x * 64;
    int nh = blockIdx.y;
    int n = nh >> 2, h = nh & 3;
    const float* qb = qkv + ((size_t)n * 768 + h * 64) * HW;
    const float* kb = qb + (size_t)256 * HW;
    const float* vb = qb + (size_t)512 * HW;
    int d = t >> 2;            // 0..63
    int rr = (t & 3) << 4;     // 0,16,32,48
#pragma unroll
    for (int i = 0; i < 16; i += 4) {
        *(float4*)&Qs[d][rr + i] = *(const float4*)(qb + (size_t)d * HW + q0 + rr + i);
    }
    if (t < 64) { mrow[t] = -1e30f; lrow[t] = 0.f; }
    float Oa[16];
#pragma unroll
    for (int i = 0; i < 16; i++) Oa[i] = 0.f;
    const float scale = 0.125f;
    int r = t >> 2;
    int j0 = (t & 3) << 4;
    for (int kt = 0; kt < 64; kt++) {
        int kp = kt * 64;
        // load K,V tiles (padded rows -> scalar LDS stores)
#pragma unroll
        for (int i = 0; i < 16; i += 4) {
            float4 kv = *(const float4*)(kb + (size_t)d * HW + kp + rr + i);
            KS[d][rr + i] = kv.x; KS[d][rr + i + 1] = kv.y; KS[d][rr + i + 2] = kv.z; KS[d][rr + i + 3] = kv.w;
            float4 vv = *(const float4*)(vb + (size_t)d * HW + kp + rr + i);
            Vs[d][rr + i] = vv.x; Vs[d][rr + i + 1] = vv.y; Vs[d][rr + i + 2] = vv.z; Vs[d][rr + i + 3] = vv.w;
        }
        __syncthreads();
        // scores into registers: thread (r, j0..j0+15)
        float s[16];
#pragma unroll
        for (int jj = 0; jj < 16; jj++) s[jj] = 0.f;
#pragma unroll 4
        for (int dd = 0; dd < 64; dd++) {
            float qv = Qs[dd][r];
#pragma unroll
            for (int jj = 0; jj < 16; jj++) s[jj] += qv * KS[dd][j0 + jj];
        }
        __syncthreads();  // everyone done reading K; reuse KS as score buffer
#pragma unroll
        for (int jj = 0; jj < 16; jj++) KS[r][j0 + jj] = s[jj] * scale;
        __syncthreads();
        // online softmax row pass
        if (t < 64) {
            float mold = mrow[t];
            float mx = mold;
#pragma unroll 8
            for (int j = 0; j < 64; j++) mx = fmaxf(mx, KS[t][j]);
            float alpha = __expf(mold - mx);
            float sum = 0.f;
#pragma unroll 8
            for (int j = 0; j < 64; j++) {
                float p = __expf(KS[t][j] - mx);
                KS[t][j] = p;
                sum += p;
            }
            mrow[t] = mx;
            lrow[t] = lrow[t] * alpha + sum;
            arow[t] = alpha;
        }
        __syncthreads();
        // PV: thread owns col d, rows rr..rr+15
#pragma unroll
        for (int i = 0; i < 16; i++) Oa[i] *= arow[rr + i];
#pragma unroll 4
        for (int j = 0; j < 64; j++) {
            float vv = Vs[d][j];
#pragma unroll
            for (int i = 0; i < 16; i++) Oa[i] += KS[rr + i][j] * vv;
        }
        __syncthreads();  // before next tile overwrites KS/Vs
    }
    float* ob = attn + ((size_t)n * 256 + h * 64 + d) * HW + q0;
#pragma unroll
    for (int i = 0; i < 16; i++) {
        ob[rr + i] = Oa[i] / lrow[rr + i];
    }
}

// ---------------- Proj GEMM fused with bias + residual + mask, fp32 out ----------------
__global__ __launch_bounds__(256) void proj_gemm(const float* __restrict__ attn, const float* __restrict__ wp,
                                                 const float* __restrict__ bp, const float* __restrict__ x,
                                                 const float* __restrict__ mask, float* __restrict__ out) {
    __shared__ float Xs[16][64];
    __shared__ float Ws[64][16];
    int t = threadIdx.x;
    int p0 = blockIdx.x * 64;
    int o0 = blockIdx.y * 64;
    int n = blockIdx.z;
    int pl = t & 63, og = t >> 6;
    float acc[16];
#pragma unroll
    for (int i = 0; i < 16; i++) acc[i] = 0.f;
    const float* abase = attn + (size_t)n * CCH * HW + p0;
    for (int cs = 0; cs < 256; cs += 16) {
        {
            int idx = t * 4; int row = idx >> 6; int col = idx & 63;
            *(float4*)&Xs[row][col] = *(const float4*)(abase + (size_t)(cs + row) * HW + col);
        }
        {
            int idx = t * 4; int ol = idx >> 4; int cc = idx & 15;
            float4 v = *(const float4*)(wp + (size_t)(o0 + ol) * 256 + cs + cc);
            Ws[ol][cc] = v.x;
            Ws[ol][cc + 1] = v.y;
            Ws[ol][cc + 2] = v.z;
            Ws[ol][cc + 3] = v.w;
        }
        __syncthreads();
#pragma unroll
        for (int cc = 0; cc < 16; cc++) {
            float xv = Xs[cc][pl];
#pragma unroll
            for (int i = 0; i < 16; i++) acc[i] += Ws[og * 16 + i][cc] * xv;
        }
        __syncthreads();
    }
    const float* xb = x + ((size_t)n * CCH + o0) * HW + p0;
    const float* mb = mask + (size_t)n * HW + p0;
    float* ob = out + ((size_t)n * CCH + o0) * HW + p0;
    float mv = mb[pl];
#pragma unroll
    for (int i = 0; i < 16; i++) {
        int o = og * 16 + i;
        float val = acc[i] + bp[o0 + o];
        float xv = xb[(size_t)o * HW + pl];
        ob[(size_t)o * HW + pl] = (xv + val) * mv;
    }
}

// ---------------- mask passthrough ----------------
__global__ __launch_bounds__(256) void mask_copy(const float* __restrict__ mask, float* __restrict__ out) {
    int i = blockIdx.x * 256 + threadIdx.x;
    out[i] = mask[i];  // exactly 16384 launched
}

extern "C" void kernel_launch(void* const* d_in, const int* in_sizes, int n_in,
                              void* d_out, int out_size, void* d_ws, size_t ws_size,
                              hipStream_t stream) {
    const float* x = (const float*)d_in[0];
    const float* mask = (const float*)d_in[1];
    const float* norm_w = (const float*)d_in[2];
    const float* norm_b = (const float*)d_in[3];
    const float* qkv_w = (const float*)d_in[4];
    const float* qkv_b = (const float*)d_in[5];
    const float* proj_w = (const float*)d_in[6];
    const float* proj_b = (const float*)d_in[7];
    float* out = (float*)d_out;

    float* ws = (float*)d_ws;
    float* xn = ws;                       // 4,194,304 f32
    float* qkv = ws + 4194304;            // 12,582,912 f32
    float* attn = ws + 16777216;          // 4,194,304 f32
    float* stats = ws + 20971520;         // 64 f32

    gn_stats<<<32, 256, 0, stream>>>(x, stats);
    gn_apply<<<4096, 256, 0, stream>>>(x, norm_w, norm_b, stats, xn);
    qkv_gemm<<<dim3(64, 12, 4), 256, 0, stream>>>(xn, qkv_w, qkv_b, qkv);
    flash_attn<<<dim3(64, 16), 256, 0, stream>>>(qkv, attn);
    proj_gemm<<<dim3(64, 4, 4), 256, 0, stream>>>(attn, proj_w, proj_b, x, mask, out);
    mask_copy<<<64, 256, 0, stream>>>(mask, out + 4194304);
}

// Round 3
// 544.209 us; speedup vs baseline: 6.9267x; 6.9267x over previous
//
#include <hip/hip_runtime.h>

#define HW 4096
#define EPSV 1e-5f

typedef unsigned short u16;
typedef unsigned int u32;
typedef __attribute__((ext_vector_type(8))) short short8;   // 8 bf16 = 4 VGPRs (MFMA A/B frag)
typedef __attribute__((ext_vector_type(4))) float f32x4;    // MFMA C/D frag

#define MFMA16(a, b, c) __builtin_amdgcn_mfma_f32_16x16x32_bf16((a), (b), (c), 0, 0, 0)
#define GLDS(g, l) __builtin_amdgcn_global_load_lds( \
    (const __attribute__((address_space(1))) u16*)(g), \
    (__attribute__((address_space(3))) u16*)(l), 16, 0, 0)

__device__ __forceinline__ u16 f2b(float f) {
    u32 u = __float_as_uint(f);
    u32 r = (u + 0x7FFFu + ((u >> 16) & 1u)) >> 16;
    return (u16)r;
}

// ---------------- GroupNorm stats: one block per (n, g) ----------------
__global__ __launch_bounds__(256) void gn_stats(const float* __restrict__ x, float* __restrict__ stats) {
    int grp = blockIdx.x;
    const float4* base = (const float4*)(x + (size_t)grp * 32 * HW);
    int t = threadIdx.x;
    float s = 0.f, sq = 0.f;
    for (int i = t; i < 32768; i += 256) {
        float4 v = base[i];
        s += v.x + v.y + v.z + v.w;
        sq += v.x * v.x + v.y * v.y + v.z * v.z + v.w * v.w;
    }
    __shared__ float rs[256], rq[256];
    rs[t] = s; rq[t] = sq;
    __syncthreads();
    for (int o = 128; o > 0; o >>= 1) {
        if (t < o) { rs[t] += rs[t + o]; rq[t] += rq[t + o]; }
        __syncthreads();
    }
    if (t == 0) {
        float mean = rs[0] * (1.f / 131072.f);
        float var = rq[0] * (1.f / 131072.f) - mean * mean;
        stats[grp] = mean;
        stats[32 + grp] = rsqrtf(var + EPSV);
    }
}

// ---------------- GroupNorm apply -> fp32 x_norm ----------------
__global__ __launch_bounds__(256) void gn_apply(const float* __restrict__ x, const float* __restrict__ w,
                                                const float* __restrict__ b, const float* __restrict__ stats,
                                                float* __restrict__ xn) {
    int idx = blockIdx.x * 256 + threadIdx.x;
    int base = idx * 4;
    int c = (base >> 12) & 255;
    int n = base >> 20;
    int grp = n * 8 + (c >> 5);
    float mean = stats[grp], rstd = stats[32 + grp];
    float a = rstd * w[c];
    float bb = b[c] - mean * a;
    float4 v = *(const float4*)(x + base);
    float4 o;
    o.x = v.x * a + bb;
    o.y = v.y * a + bb;
    o.z = v.z * a + bb;
    o.w = v.w * a + bb;
    *(float4*)(xn + base) = o;
}

// ---------------- QKV GEMM -> bf16 outputs in MFMA-friendly layouts ----------------
// Q,K: [nh][p][d] bf16 (Q scaled by 0.125, bias included). V: [nh][d][p] bf16.
__global__ __launch_bounds__(256) void qkv_gemm(const float* __restrict__ xn, const float* __restrict__ wq,
                                                const float* __restrict__ bq, u16* __restrict__ Qw,
                                                u16* __restrict__ Kw, u16* __restrict__ Vw) {
    __shared__ float Xs[16][64];
    __shared__ float Ws[64][16];
    __shared__ u16 Ts[64][72];
    int t = threadIdx.x;
    int p0 = blockIdx.x * 64;
    int o0 = blockIdx.y * 64;
    int n = blockIdx.z;
    int pl = t & 63, og = t >> 6;
    float acc[16];
#pragma unroll
    for (int i = 0; i < 16; i++) acc[i] = 0.f;
    const float* xbase = xn + (size_t)n * 256 * HW + p0;
    for (int cs = 0; cs < 256; cs += 16) {
        {
            int idx = t * 4; int row = idx >> 6; int colx = idx & 63;
            *(float4*)&Xs[row][colx] = *(const float4*)(xbase + (size_t)(cs + row) * HW + colx);
        }
        {
            int idx = t * 4; int ol = idx >> 4; int cc = idx & 15;
            float4 v = *(const float4*)(wq + (size_t)(o0 + ol) * 256 + cs + cc);
            Ws[ol][cc] = v.x; Ws[ol][cc + 1] = v.y; Ws[ol][cc + 2] = v.z; Ws[ol][cc + 3] = v.w;
        }
        __syncthreads();
#pragma unroll
        for (int cc = 0; cc < 16; cc++) {
            float xv = Xs[cc][pl];
#pragma unroll
            for (int i = 0; i < 16; i++) acc[i] += Ws[og * 16 + i][cc] * xv;
        }
        __syncthreads();
    }
    int type = o0 >> 8;        // 0=q, 1=k, 2=v (o-tile == one head of one of q/k/v)
    int h = (o0 >> 6) & 3;
    int nh = n * 4 + h;
    if (type == 2) {
        u16* vb = Vw + (size_t)nh * 64 * HW + p0 + pl;
#pragma unroll
        for (int i = 0; i < 16; i++) {
            int o = og * 16 + i;
            vb[(size_t)o * HW] = f2b(acc[i] + bq[o0 + o]);
        }
    } else {
        float scale = (type == 0) ? 0.125f : 1.0f;
#pragma unroll
        for (int i = 0; i < 16; i++) {
            int o = og * 16 + i;
            Ts[pl][o] = f2b((acc[i] + bq[o0 + o]) * scale);
        }
        __syncthreads();
        u16* dst = (type == 0 ? Qw : Kw) + ((size_t)nh * HW + p0) * 64;
        int p = t >> 2, ck = t & 3;
        short8 lo = *(const short8*)&Ts[p][ck * 16];
        short8 hi = *(const short8*)&Ts[p][ck * 16 + 8];
        *(short8*)(dst + (size_t)p * 64 + ck * 16) = lo;
        *(short8*)(dst + (size_t)p * 64 + ck * 16 + 8) = hi;
    }
}

// ---------------- MFMA flash attention ----------------
// grid (64 q-tiles, 16 nh), block 256 (4 waves). Wave w owns q-rows q0+16w..+15.
// Ks[kidx][d], Vts[d][j]: bf16, 16B chunks XOR-swizzled (chunk c of row r at slot c^(r&7)).
__global__ __launch_bounds__(256) void flash_mfma(const u16* __restrict__ Qw, const u16* __restrict__ Kw,
                                                  const u16* __restrict__ Vw, float* __restrict__ attn) {
    __shared__ u16 Ks[64 * 64];
    __shared__ u16 Vts[64 * 64];
    __shared__ u16 Ps[4][16 * 72];
    int t = threadIdx.x;
    int w = t >> 6, lane = t & 63;
    int col = lane & 15, quad = lane >> 4;
    int q0 = blockIdx.x * 64;
    int nh = blockIdx.y;

    // Q A-fragments in registers: A[m=lane&15][k=quad*8+j], two k-steps
    const u16* qp = Qw + ((size_t)nh * HW + q0 + w * 16 + col) * 64 + quad * 8;
    short8 qa0 = *(const short8*)qp;
    short8 qa1 = *(const short8*)(qp + 32);

    f32x4 Oac[4];
#pragma unroll
    for (int db = 0; db < 4; db++) Oac[db] = (f32x4){0.f, 0.f, 0.f, 0.f};
    float mI[4], lI[4];
#pragma unroll
    for (int rg = 0; rg < 4; rg++) { mI[rg] = -1e30f; lI[rg] = 0.f; }

    const u16* kbase = Kw + (size_t)nh * HW * 64;  // [p][d]
    const u16* vbase = Vw + (size_t)nh * 64 * HW;  // [d][p]
    int r0 = w * 8 + (lane >> 3);   // staging row (call 0); call 1: +32
    int cc = lane & 7;              // chunk slot within row

    for (int kt = 0; kt < 64; kt++) {
        int kp = kt * 64;
        {
            int r1 = r0, r2 = r0 + 32;
            GLDS(kbase + (size_t)(kp + r1) * 64 + (cc ^ (r1 & 7)) * 8, Ks + (w * 8) * 64);
            GLDS(kbase + (size_t)(kp + r2) * 64 + (cc ^ (r2 & 7)) * 8, Ks + (w * 8 + 32) * 64);
            GLDS(vbase + (size_t)r1 * HW + kp + (cc ^ (r1 & 7)) * 8, Vts + (w * 8) * 64);
            GLDS(vbase + (size_t)r2 * HW + kp + (cc ^ (r2 & 7)) * 8, Vts + (w * 8 + 32) * 64);
        }
        __syncthreads();

        // S = Q K^T : 4 j-blocks of 16, each 2 k-steps
        f32x4 s[4];
#pragma unroll
        for (int jb = 0; jb < 4; jb++) {
            int krow = jb * 16 + col;
            const u16* kr = Ks + krow * 64;
            short8 kb0 = *(const short8*)(kr + ((quad ^ (krow & 7)) * 8));
            short8 kb1 = *(const short8*)(kr + (((quad + 4) ^ (krow & 7)) * 8));
            f32x4 a = (f32x4){0.f, 0.f, 0.f, 0.f};
            a = MFMA16(qa0, kb0, a);
            a = MFMA16(qa1, kb1, a);
            s[jb] = a;
        }

        // online softmax; row = quad*4+rg, cols spread over lane bits 0..3 (x4 jb)
        float pb[4][4];
        float alpha[4];
#pragma unroll
        for (int rg = 0; rg < 4; rg++) {
            float tm = fmaxf(fmaxf(s[0][rg], s[1][rg]), fmaxf(s[2][rg], s[3][rg]));
            tm = fmaxf(tm, __shfl_xor(tm, 1));
            tm = fmaxf(tm, __shfl_xor(tm, 2));
            tm = fmaxf(tm, __shfl_xor(tm, 4));
            tm = fmaxf(tm, __shfl_xor(tm, 8));
            float mnew = fmaxf(mI[rg], tm);
            float al = __expf(mI[rg] - mnew);
            float rs = 0.f;
#pragma unroll
            for (int jb = 0; jb < 4; jb++) {
                float p = __expf(s[jb][rg] - mnew);
                pb[jb][rg] = p;
                rs += p;
            }
            rs += __shfl_xor(rs, 1);
            rs += __shfl_xor(rs, 2);
            rs += __shfl_xor(rs, 4);
            rs += __shfl_xor(rs, 8);
            lI[rg] = lI[rg] * al + rs;
            mI[rg] = mnew;
            alpha[rg] = al;
        }

        // P: C-layout -> LDS (wave-private, padded 72) -> A-layout
        u16* pw = &Ps[w][0];
#pragma unroll
        for (int jb = 0; jb < 4; jb++)
#pragma unroll
            for (int rg = 0; rg < 4; rg++)
                pw[(quad * 4 + rg) * 72 + jb * 16 + col] = f2b(pb[jb][rg]);
#pragma unroll
        for (int db = 0; db < 4; db++) {
            Oac[db][0] *= alpha[0];
            Oac[db][1] *= alpha[1];
            Oac[db][2] *= alpha[2];
            Oac[db][3] *= alpha[3];
        }
        const u16* pr = &Ps[w][col * 72];
        short8 pa0 = *(const short8*)(pr + quad * 8);
        short8 pa1 = *(const short8*)(pr + 32 + quad * 8);
#pragma unroll
        for (int db = 0; db < 4; db++) {
            int vrow = db * 16 + col;
            const u16* vr = Vts + vrow * 64;
            short8 vb0 = *(const short8*)(vr + ((quad ^ (vrow & 7)) * 8));
            short8 vb1 = *(const short8*)(vr + (((quad + 4) ^ (vrow & 7)) * 8));
            Oac[db] = MFMA16(pa0, vb0, Oac[db]);
            Oac[db] = MFMA16(pa1, vb1, Oac[db]);
        }
        __syncthreads();
    }

    // epilogue: attn fp32 [nh*64 + d][q]
#pragma unroll
    for (int db = 0; db < 4; db++) {
        float* ab = attn + ((size_t)(nh * 64 + db * 16 + col)) * HW + q0 + w * 16 + quad * 4;
#pragma unroll
        for (int rg = 0; rg < 4; rg++)
            ab[rg] = Oac[db][rg] / lI[rg];
    }
}

// ---------------- Proj GEMM fused with bias + residual + mask ----------------
__global__ __launch_bounds__(256) void proj_gemm(const float* __restrict__ attn, const float* __restrict__ wp,
                                                 const float* __restrict__ bp, const float* __restrict__ x,
                                                 const float* __restrict__ mask, float* __restrict__ out) {
    __shared__ float Xs[16][64];
    __shared__ float Ws[64][16];
    int t = threadIdx.x;
    int p0 = blockIdx.x * 64;
    int o0 = blockIdx.y * 64;
    int n = blockIdx.z;
    int pl = t & 63, og = t >> 6;
    float acc[16];
#pragma unroll
    for (int i = 0; i < 16; i++) acc[i] = 0.f;
    const float* abase = attn + (size_t)n * 256 * HW + p0;
    for (int cs = 0; cs < 256; cs += 16) {
        {
            int idx = t * 4; int row = idx >> 6; int colx = idx & 63;
            *(float4*)&Xs[row][colx] = *(const float4*)(abase + (size_t)(cs + row) * HW + colx);
        }
        {
            int idx = t * 4; int ol = idx >> 4; int cc = idx & 15;
            float4 v = *(const float4*)(wp + (size_t)(o0 + ol) * 256 + cs + cc);
            Ws[ol][cc] = v.x; Ws[ol][cc + 1] = v.y; Ws[ol][cc + 2] = v.z; Ws[ol][cc + 3] = v.w;
        }
        __syncthreads();
#pragma unroll
        for (int cc = 0; cc < 16; cc++) {
            float xv = Xs[cc][pl];
#pragma unroll
            for (int i = 0; i < 16; i++) acc[i] += Ws[og * 16 + i][cc] * xv;
        }
        __syncthreads();
    }
    const float* xb = x + ((size_t)n * 256 + o0) * HW + p0;
    const float* mb = mask + (size_t)n * HW + p0;
    float* ob = out + ((size_t)n * 256 + o0) * HW + p0;
    float mv = mb[pl];
#pragma unroll
    for (int i = 0; i < 16; i++) {
        int o = og * 16 + i;
        float val = acc[i] + bp[o0 + o];
        float xv = xb[(size_t)o * HW + pl];
        ob[(size_t)o * HW + pl] = (xv + val) * mv;
    }
}

// ---------------- mask passthrough ----------------
__global__ __launch_bounds__(256) void mask_copy(const float* __restrict__ mask, float* __restrict__ out) {
    int i = blockIdx.x * 256 + threadIdx.x;
    out[i] = mask[i];
}

extern "C" void kernel_launch(void* const* d_in, const int* in_sizes, int n_in,
                              void* d_out, int out_size, void* d_ws, size_t ws_size,
                              hipStream_t stream) {
    const float* x = (const float*)d_in[0];
    const float* mask = (const float*)d_in[1];
    const float* norm_w = (const float*)d_in[2];
    const float* norm_b = (const float*)d_in[3];
    const float* qkv_w = (const float*)d_in[4];
    const float* qkv_b = (const float*)d_in[5];
    const float* proj_w = (const float*)d_in[6];
    const float* proj_b = (const float*)d_in[7];
    float* out = (float*)d_out;

    float* ws = (float*)d_ws;
    float* xn = ws;                       // 4,194,304 f32
    float* attnb = ws + 4194304;          // 4,194,304 f32
    float* stats = ws + 8388608;          // 64 f32
    u16* Qw = (u16*)(ws + 8388672);       // 4,194,304 bf16
    u16* Kw = Qw + 4194304;               // 4,194,304 bf16
    u16* Vw = Kw + 4194304;               // 4,194,304 bf16

    gn_stats<<<32, 256, 0, stream>>>(x, stats);
    gn_apply<<<4096, 256, 0, stream>>>(x, norm_w, norm_b, stats, xn);
    qkv_gemm<<<dim3(64, 12, 4), 256, 0, stream>>>(xn, qkv_w, qkv_b, Qw, Kw, Vw);
    flash_mfma<<<dim3(64, 16), 256, 0, stream>>>(Qw, Kw, Vw, attnb);
    proj_gemm<<<dim3(64, 4, 4), 256, 0, stream>>>(attnb, proj_w, proj_b, x, mask, out);
    mask_copy<<<64, 256, 0, stream>>>(mask, out + 4194304);
}

// Round 5
// 510.160 us; speedup vs baseline: 7.3889x; 1.0667x over previous
//
#include <hip/hip_runtime.h>

#define HW 4096
#define EPSV 1e-5f

typedef unsigned short u16;
typedef unsigned int u32;
typedef __attribute__((ext_vector_type(8))) short short8;    // 8 bf16 (K=32 frag)
typedef __attribute__((ext_vector_type(4))) short short4v;   // 4 bf16 (K=16 frag)
typedef __attribute__((ext_vector_type(4))) float f32x4;     // C/D frag

#define MFMA_K32(a, b, c) __builtin_amdgcn_mfma_f32_16x16x32_bf16((a), (b), (c), 0, 0, 0)
#if __has_builtin(__builtin_amdgcn_mfma_f32_16x16x16bf16_1k)
#define MFMA_K16(a, b, c) __builtin_amdgcn_mfma_f32_16x16x16bf16_1k((a), (b), (c), 0, 0, 0)
#elif __has_builtin(__builtin_amdgcn_mfma_f32_16x16x16_bf16)
#define MFMA_K16(a, b, c) __builtin_amdgcn_mfma_f32_16x16x16_bf16((a), (b), (c), 0, 0, 0)
#else
// Host-pass parse stub only: the device pass selects a real builtin above
// (proven by R4's clean gfx950 compile; host __has_builtin can't see aux-target builtins).
#define MFMA_K16(a, b, c) (c)
#endif

#define GLDS(g, l) __builtin_amdgcn_global_load_lds( \
    (const __attribute__((address_space(1))) u16*)(g), \
    (__attribute__((address_space(3))) u16*)(l), 16, 0, 0)

__device__ __forceinline__ u16 f2b(float f) {
    u32 u = __float_as_uint(f);
    u32 r = (u + 0x7FFFu + ((u >> 16) & 1u)) >> 16;
    return (u16)r;
}

// ---------------- GroupNorm stats: one block per (n, g) ----------------
__global__ __launch_bounds__(256) void gn_stats(const float* __restrict__ x, float* __restrict__ stats) {
    int grp = blockIdx.x;
    const float4* base = (const float4*)(x + (size_t)grp * 32 * HW);
    int t = threadIdx.x;
    float s = 0.f, sq = 0.f;
    for (int i = t; i < 32768; i += 256) {
        float4 v = base[i];
        s += v.x + v.y + v.z + v.w;
        sq += v.x * v.x + v.y * v.y + v.z * v.z + v.w * v.w;
    }
    __shared__ float rs[256], rq[256];
    rs[t] = s; rq[t] = sq;
    __syncthreads();
    for (int o = 128; o > 0; o >>= 1) {
        if (t < o) { rs[t] += rs[t + o]; rq[t] += rq[t + o]; }
        __syncthreads();
    }
    if (t == 0) {
        float mean = rs[0] * (1.f / 131072.f);
        float var = rq[0] * (1.f / 131072.f) - mean * mean;
        stats[grp] = mean;
        stats[32 + grp] = rsqrtf(var + EPSV);
    }
}

// ---------------- GroupNorm apply -> fp32 x_norm ----------------
__global__ __launch_bounds__(256) void gn_apply(const float* __restrict__ x, const float* __restrict__ w,
                                                const float* __restrict__ b, const float* __restrict__ stats,
                                                float* __restrict__ xn) {
    int idx = blockIdx.x * 256 + threadIdx.x;
    int base = idx * 4;
    int c = (base >> 12) & 255;
    int n = base >> 20;
    int grp = n * 8 + (c >> 5);
    float mean = stats[grp], rstd = stats[32 + grp];
    float a = rstd * w[c];
    float bb = b[c] - mean * a;
    float4 v = *(const float4*)(x + base);
    float4 o;
    o.x = v.x * a + bb;
    o.y = v.y * a + bb;
    o.z = v.z * a + bb;
    o.w = v.w * a + bb;
    *(float4*)(xn + base) = o;
}

// ---------------- QKV GEMM -> bf16 outputs in MFMA-friendly layouts ----------------
// Q,K: [nh][p][d] bf16 (Q scaled by 0.125*log2e -> softmax in exp2 domain). V: [nh][d][p] bf16.
__global__ __launch_bounds__(256) void qkv_gemm(const float* __restrict__ xn, const float* __restrict__ wq,
                                                const float* __restrict__ bq, u16* __restrict__ Qw,
                                                u16* __restrict__ Kw, u16* __restrict__ Vw) {
    __shared__ float Xs[16][64];
    __shared__ float Ws[64][16];
    __shared__ u16 Ts[64][72];
    int t = threadIdx.x;
    int p0 = blockIdx.x * 64;
    int o0 = blockIdx.y * 64;
    int n = blockIdx.z;
    int pl = t & 63, og = t >> 6;
    float acc[16];
#pragma unroll
    for (int i = 0; i < 16; i++) acc[i] = 0.f;
    const float* xbase = xn + (size_t)n * 256 * HW + p0;
    for (int cs = 0; cs < 256; cs += 16) {
        {
            int idx = t * 4; int row = idx >> 6; int colx = idx & 63;
            *(float4*)&Xs[row][colx] = *(const float4*)(xbase + (size_t)(cs + row) * HW + colx);
        }
        {
            int idx = t * 4; int ol = idx >> 4; int cc = idx & 15;
            float4 v = *(const float4*)(wq + (size_t)(o0 + ol) * 256 + cs + cc);
            Ws[ol][cc] = v.x; Ws[ol][cc + 1] = v.y; Ws[ol][cc + 2] = v.z; Ws[ol][cc + 3] = v.w;
        }
        __syncthreads();
#pragma unroll
        for (int cc = 0; cc < 16; cc++) {
            float xv = Xs[cc][pl];
#pragma unroll
            for (int i = 0; i < 16; i++) acc[i] += Ws[og * 16 + i][cc] * xv;
        }
        __syncthreads();
    }
    int type = o0 >> 8;        // 0=q, 1=k, 2=v
    int h = (o0 >> 6) & 3;
    int nh = n * 4 + h;
    if (type == 2) {
        u16* vb = Vw + (size_t)nh * 64 * HW + p0 + pl;
#pragma unroll
        for (int i = 0; i < 16; i++) {
            int o = og * 16 + i;
            vb[(size_t)o * HW] = f2b(acc[i] + bq[o0 + o]);
        }
    } else {
        float scale = (type == 0) ? (0.125f * 1.44269504088896341f) : 1.0f;
#pragma unroll
        for (int i = 0; i < 16; i++) {
            int o = og * 16 + i;
            Ts[pl][o] = f2b((acc[i] + bq[o0 + o]) * scale);
        }
        __syncthreads();
        u16* dst = (type == 0 ? Qw : Kw) + ((size_t)nh * HW + p0) * 64;
        int p = t >> 2, ck = t & 3;
        short8 lo = *(const short8*)&Ts[p][ck * 16];
        short8 hi = *(const short8*)&Ts[p][ck * 16 + 8];
        *(short8*)(dst + (size_t)p * 64 + ck * 16) = lo;
        *(short8*)(dst + (size_t)p * 64 + ck * 16 + 8) = hi;
    }
}

// ---------------- MFMA flash attention, transposed-S formulation ----------------
// grid (64 q-tiles, 16 nh), block 256 (4 waves). Wave w owns q-rows q0+16w..+15.
// S^T = K·Q^T (A=K-frag from LDS, B=Q regs); P^T stays in registers in the exact
// B-frag layout of mfma_16x16x16; O^T = V^T·P^T. No P LDS round-trip, 2 shuffles
// per softmax reduction, double-buffered K/V staging, 1 barrier/tile.
__global__ __launch_bounds__(256) void flash_mfma(const u16* __restrict__ Qw, const u16* __restrict__ Kw,
                                                  const u16* __restrict__ Vw, float* __restrict__ attn) {
    __shared__ u16 Ks[2][4096];   // [j][d], 16B chunks xor-swizzled by row&7
    __shared__ u16 Vts[2][4096];  // [d][j], same swizzle
    int t = threadIdx.x;
    int w = t >> 6, lane = t & 63;
    int col = lane & 15, quad = lane >> 4;
    int q0 = blockIdx.x * 64;
    int nh = blockIdx.y;

    // Q fragments (serve as B-operands of S^T MFMA): Q[q=col][d=quad*8+j (+32)]
    const u16* qp = Qw + ((size_t)nh * HW + q0 + w * 16 + col) * 64 + quad * 8;
    short8 qb0 = *(const short8*)qp;
    short8 qb1 = *(const short8*)(qp + 32);

    f32x4 Oac[4];
#pragma unroll
    for (int db = 0; db < 4; db++) Oac[db] = (f32x4){0.f, 0.f, 0.f, 0.f};
    float mI = -1e30f, lI = 0.f;   // per-lane state for column q = col (log2 domain)

    const u16* kbase = Kw + (size_t)nh * HW * 64;  // [p][d]
    const u16* vbase = Vw + (size_t)nh * 64 * HW;  // [d][p]
    int lr = lane >> 3;            // staging row within wave chunk (0..7)
    int cc = lane & 7;             // chunk slot
    int xo = (cc ^ lr) * 8;        // xor-swizzled source chunk offset (u16)
    size_t kOff1 = (size_t)(w * 8 + lr) * 64 + xo;
    size_t kOff2 = (size_t)(w * 8 + lr + 32) * 64 + xo;
    size_t vOff1 = (size_t)(w * 8 + lr) * HW + xo;
    size_t vOff2 = (size_t)(w * 8 + lr + 32) * HW + xo;

#define STAGE(kt_, b_) do { \
        int kp_ = (kt_) * 64; \
        GLDS(kbase + (size_t)kp_ * 64 + kOff1, &Ks[b_][w * 512]); \
        GLDS(kbase + (size_t)kp_ * 64 + kOff2, &Ks[b_][w * 512 + 2048]); \
        GLDS(vbase + kp_ + vOff1, &Vts[b_][w * 512]); \
        GLDS(vbase + kp_ + vOff2, &Vts[b_][w * 512 + 2048]); \
    } while (0)

    STAGE(0, 0);
    __syncthreads();

    int c7 = col & 7;
    for (int kt = 0; kt < 64; kt++) {
        int cur = kt & 1;
        if (kt < 63) STAGE(kt + 1, cur ^ 1);   // prefetch overlaps with compute below
        const u16* KsC = Ks[cur];
        const u16* VtC = Vts[cur];

        // S^T tiles: rows j = jb*16 + quad*4 + rg, col q = col
        f32x4 st[4];
#pragma unroll
        for (int jb = 0; jb < 4; jb++) {
            const u16* kr = KsC + (jb * 16 + col) * 64;
            short8 ka0 = *(const short8*)(kr + ((quad ^ c7) * 8));
            short8 ka1 = *(const short8*)(kr + (((quad + 4) ^ c7) * 8));
            f32x4 a = (f32x4){0.f, 0.f, 0.f, 0.f};
            a = MFMA_K32(ka0, qb0, a);
            a = MFMA_K32(ka1, qb1, a);
            st[jb] = a;
        }

        // softmax over j: in-register max/sum + 2 cross-quad shuffles
        float tm = st[0][0];
#pragma unroll
        for (int jb = 0; jb < 4; jb++)
#pragma unroll
            for (int rg = 0; rg < 4; rg++) tm = fmaxf(tm, st[jb][rg]);
        tm = fmaxf(tm, __shfl_xor(tm, 16));
        tm = fmaxf(tm, __shfl_xor(tm, 32));
        float mnew = fmaxf(mI, tm);
        float al = __builtin_amdgcn_exp2f(mI - mnew);
        mI = mnew;
        float ps[4][4];
        float rsum = 0.f;
#pragma unroll
        for (int jb = 0; jb < 4; jb++)
#pragma unroll
            for (int rg = 0; rg < 4; rg++) {
                float p = __builtin_amdgcn_exp2f(st[jb][rg] - mnew);
                ps[jb][rg] = p;
                rsum += p;
            }
        rsum += __shfl_xor(rsum, 16);
        rsum += __shfl_xor(rsum, 32);
        lI = lI * al + rsum;

        // P^T fragments: B-layout of 16x16x16 (k = quad*4 + rg), truncate to bf16
        short4v pt[4];
#pragma unroll
        for (int jb = 0; jb < 4; jb++)
#pragma unroll
            for (int rg = 0; rg < 4; rg++)
                pt[jb][rg] = (short)(__float_as_uint(ps[jb][rg]) >> 16);

#pragma unroll
        for (int db = 0; db < 4; db++) {
            Oac[db][0] *= al; Oac[db][1] *= al; Oac[db][2] *= al; Oac[db][3] *= al;
        }

        // O^T += V^T · P^T : A-frag = V^T[d = db*16+col][j = jb*16 + quad*4 .. +3]
#pragma unroll
        for (int db = 0; db < 4; db++) {
            const u16* vr = VtC + (db * 16 + col) * 64;
#pragma unroll
            for (int jb = 0; jb < 4; jb++) {
                int c = 2 * jb + (quad >> 1);
                short4v va = *(const short4v*)(vr + ((c ^ c7) * 8) + (quad & 1) * 4);
                Oac[db] = MFMA_K16(va, pt[jb], Oac[db]);
            }
        }
        __syncthreads();   // drains prefetch vmcnt + guards buffer reuse
    }
#undef STAGE

    // epilogue: attn fp32 [nh*64 + d][q];  O^T C-layout: row d = db*16+quad*4+rg, col q
    float rl = 1.0f / lI;
#pragma unroll
    for (int db = 0; db < 4; db++) {
        float* ab = attn + ((size_t)(nh * 64 + db * 16 + quad * 4)) * HW + q0 + w * 16 + col;
#pragma unroll
        for (int rg = 0; rg < 4; rg++)
            ab[(size_t)rg * HW] = Oac[db][rg] * rl;
    }
}

// ---------------- Proj GEMM fused with bias + residual + mask ----------------
__global__ __launch_bounds__(256) void proj_gemm(const float* __restrict__ attn, const float* __restrict__ wp,
                                                 const float* __restrict__ bp, const float* __restrict__ x,
                                                 const float* __restrict__ mask, float* __restrict__ out) {
    __shared__ float Xs[16][64];
    __shared__ float Ws[64][16];
    int t = threadIdx.x;
    int p0 = blockIdx.x * 64;
    int o0 = blockIdx.y * 64;
    int n = blockIdx.z;
    int pl = t & 63, og = t >> 6;
    float acc[16];
#pragma unroll
    for (int i = 0; i < 16; i++) acc[i] = 0.f;
    const float* abase = attn + (size_t)n * 256 * HW + p0;
    for (int cs = 0; cs < 256; cs += 16) {
        {
            int idx = t * 4; int row = idx >> 6; int colx = idx & 63;
            *(float4*)&Xs[row][colx] = *(const float4*)(abase + (size_t)(cs + row) * HW + colx);
        }
        {
            int idx = t * 4; int ol = idx >> 4; int cc = idx & 15;
            float4 v = *(const float4*)(wp + (size_t)(o0 + ol) * 256 + cs + cc);
            Ws[ol][cc] = v.x; Ws[ol][cc + 1] = v.y; Ws[ol][cc + 2] = v.z; Ws[ol][cc + 3] = v.w;
        }
        __syncthreads();
#pragma unroll
        for (int cc = 0; cc < 16; cc++) {
            float xv = Xs[cc][pl];
#pragma unroll
            for (int i = 0; i < 16; i++) acc[i] += Ws[og * 16 + i][cc] * xv;
        }
        __syncthreads();
    }
    const float* xb = x + ((size_t)n * 256 + o0) * HW + p0;
    const float* mb = mask + (size_t)n * HW + p0;
    float* ob = out + ((size_t)n * 256 + o0) * HW + p0;
    float mv = mb[pl];
#pragma unroll
    for (int i = 0; i < 16; i++) {
        int o = og * 16 + i;
        float val = acc[i] + bp[o0 + o];
        float xv = xb[(size_t)o * HW + pl];
        ob[(size_t)o * HW + pl] = (xv + val) * mv;
    }
}

// ---------------- mask passthrough ----------------
__global__ __launch_bounds__(256) void mask_copy(const float* __restrict__ mask, float* __restrict__ out) {
    int i = blockIdx.x * 256 + threadIdx.x;
    out[i] = mask[i];
}

extern "C" void kernel_launch(void* const* d_in, const int* in_sizes, int n_in,
                              void* d_out, int out_size, void* d_ws, size_t ws_size,
                              hipStream_t stream) {
    const float* x = (const float*)d_in[0];
    const float* mask = (const float*)d_in[1];
    const float* norm_w = (const float*)d_in[2];
    const float* norm_b = (const float*)d_in[3];
    const float* qkv_w = (const float*)d_in[4];
    const float* qkv_b = (const float*)d_in[5];
    const float* proj_w = (const float*)d_in[6];
    const float* proj_b = (const float*)d_in[7];
    float* out = (float*)d_out;

    float* ws = (float*)d_ws;
    float* xn = ws;                       // 4,194,304 f32
    float* attnb = ws + 4194304;          // 4,194,304 f32
    float* stats = ws + 8388608;          // 64 f32
    u16* Qw = (u16*)(ws + 8388672);       // 4,194,304 bf16
    u16* Kw = Qw + 4194304;               // 4,194,304 bf16
    u16* Vw = Kw + 4194304;               // 4,194,304 bf16

    gn_stats<<<32, 256, 0, stream>>>(x, stats);
    gn_apply<<<4096, 256, 0, stream>>>(x, norm_w, norm_b, stats, xn);
    qkv_gemm<<<dim3(64, 12, 4), 256, 0, stream>>>(xn, qkv_w, qkv_b, Qw, Kw, Vw);
    flash_mfma<<<dim3(64, 16), 256, 0, stream>>>(Qw, Kw, Vw, attnb);
    proj_gemm<<<dim3(64, 4, 4), 256, 0, stream>>>(attnb, proj_w, proj_b, x, mask, out);
    mask_copy<<<64, 256, 0, stream>>>(mask, out + 4194304);
}

// Round 6
// 307.204 us; speedup vs baseline: 12.2705x; 1.6607x over previous
//
#include <hip/hip_runtime.h>

#define HW 4096
#define EPSV 1e-5f
#define SCL (0.125f * 1.44269504088896341f)   // 1/sqrt(64) * log2(e): softmax in exp2 domain

typedef unsigned short u16;
typedef unsigned int u32;
typedef __attribute__((ext_vector_type(8))) short short8;    // 8 bf16 (K=32 frag)
typedef __attribute__((ext_vector_type(4))) short short4v;   // 4 bf16 (K=16 frag)
typedef __attribute__((ext_vector_type(4))) float f32x4;     // C/D frag

#define MFMA_K32(a, b, c) __builtin_amdgcn_mfma_f32_16x16x32_bf16((a), (b), (c), 0, 0, 0)
#if __has_builtin(__builtin_amdgcn_mfma_f32_16x16x16bf16_1k)
#define MFMA_K16(a, b, c) __builtin_amdgcn_mfma_f32_16x16x16bf16_1k((a), (b), (c), 0, 0, 0)
#elif __has_builtin(__builtin_amdgcn_mfma_f32_16x16x16_bf16)
#define MFMA_K16(a, b, c) __builtin_amdgcn_mfma_f32_16x16x16_bf16((a), (b), (c), 0, 0, 0)
#else
// Host-pass parse stub only: the device pass selects a real builtin above.
#define MFMA_K16(a, b, c) (c)
#endif

#define GLDS(g, l) __builtin_amdgcn_global_load_lds( \
    (const __attribute__((address_space(1))) u16*)(g), \
    (__attribute__((address_space(3))) u16*)(l), 16, 0, 0)

__device__ __forceinline__ u16 f2b(float f) {
    u32 u = __float_as_uint(f);
    u32 r = (u + 0x7FFFu + ((u >> 16) & 1u)) >> 16;
    return (u16)r;
}

// ---------------- GroupNorm stage A: 512 blocks, partial sums ----------------
__global__ __launch_bounds__(256) void gn_partial(const float* __restrict__ x, float* __restrict__ ps) {
    int bid = blockIdx.x;                       // grp = bid>>4, slice = bid&15 (flat)
    const float4* base = (const float4*)x + (size_t)bid * 2048;
    int t = threadIdx.x;
    float s = 0.f, sq = 0.f;
    for (int i = t; i < 2048; i += 256) {
        float4 v = base[i];
        s += v.x + v.y + v.z + v.w;
        sq += v.x * v.x + v.y * v.y + v.z * v.z + v.w * v.w;
    }
    __shared__ float rs[256], rq[256];
    rs[t] = s; rq[t] = sq;
    __syncthreads();
    for (int o = 128; o > 0; o >>= 1) {
        if (t < o) { rs[t] += rs[t + o]; rq[t] += rq[t + o]; }
        __syncthreads();
    }
    if (t == 0) { ps[2 * bid] = rs[0]; ps[2 * bid + 1] = rq[0]; }
}

// ---------------- GroupNorm stage B: finalize 32 groups ----------------
__global__ __launch_bounds__(64) void gn_final(const float* __restrict__ ps, float* __restrict__ stats) {
    int t = threadIdx.x;
    if (t < 32) {
        float s = 0.f, sq = 0.f;
        for (int i = 0; i < 16; i++) {
            s += ps[2 * (t * 16 + i)];
            sq += ps[2 * (t * 16 + i) + 1];
        }
        float mean = s * (1.f / 131072.f);
        float var = sq * (1.f / 131072.f) - mean * mean;
        stats[t] = mean;
        stats[32 + t] = rsqrtf(var + EPSV);
    }
}

// ---------------- weight fp32 -> bf16 (rows < nscaled get * SCL) ----------------
__global__ __launch_bounds__(256) void wconv(const float* __restrict__ src, u16* __restrict__ dst, int nscaled) {
    int idx = blockIdx.x * 256 + threadIdx.x;   // one per 4 elements, grid sized exactly
    int row = idx >> 6;
    float sc = (row < nscaled) ? SCL : 1.0f;
    float4 v = *((const float4*)src + idx);
    u32 lo = (u32)f2b(v.x * sc) | ((u32)f2b(v.y * sc) << 16);
    u32 hi = (u32)f2b(v.z * sc) | ((u32)f2b(v.w * sc) << 16);
    uint2 o; o.x = lo; o.y = hi;
    *(uint2*)(dst + (size_t)idx * 4) = o;
}

// ---------------- GroupNorm apply + transpose -> bf16 xt[n][p][c] ----------------
// grid (64 p-tiles, 4 c-tiles, 4 n), block 256.
__global__ __launch_bounds__(256) void gn_apply_t(const float* __restrict__ x, const float* __restrict__ w,
                                                  const float* __restrict__ b, const float* __restrict__ stats,
                                                  u16* __restrict__ xt) {
    __shared__ u16 Tt[64][72];
    int t = threadIdx.x;
    int p0 = blockIdx.x * 64;
    int c0 = blockIdx.y * 64;
    int n = blockIdx.z;
    int pc = (t & 15) * 4;
#pragma unroll
    for (int jj = 0; jj < 4; jj++) {
        int r = (t >> 4) + jj * 16;
        int c = c0 + r;
        int grp = n * 8 + (c >> 5);
        float mean = stats[grp], rstd = stats[32 + grp];
        float a = rstd * w[c];
        float bb = b[c] - mean * a;
        float4 v = *(const float4*)(x + ((size_t)n * 256 + c) * HW + p0 + pc);
        Tt[pc + 0][r] = f2b(v.x * a + bb);
        Tt[pc + 1][r] = f2b(v.y * a + bb);
        Tt[pc + 2][r] = f2b(v.z * a + bb);
        Tt[pc + 3][r] = f2b(v.w * a + bb);
    }
    __syncthreads();
    int p = t >> 2, ck = t & 3;
    short8 s0 = *(const short8*)&Tt[p][ck * 16];
    short8 s1 = *(const short8*)&Tt[p][ck * 16 + 8];
    u16* dst = xt + ((size_t)n * HW + p0 + p) * 256 + c0 + ck * 16;
    *(short8*)dst = s0;
    *(short8*)(dst + 8) = s1;
}

// ---------------- QKV MFMA GEMM ----------------
// qkv[o][p] = W[o][c] xt^T[c][p] (+bias). grid (64 p, 12 o, 4 n), block 256 (4 waves).
// Wave w: o-strip o0+w*16..+15, p full 64. X-tile staged 16B-chunk xor-swizzled.
__global__ __launch_bounds__(256) void qkv_mfma(const u16* __restrict__ xt, const u16* __restrict__ Wb,
                                                const float* __restrict__ bq, u16* __restrict__ Qw,
                                                u16* __restrict__ Kw, u16* __restrict__ Vw) {
    __shared__ u16 Xs[64 * 256];   // [p][c], chunk c/8 xor-swizzled by p&7
    int t = threadIdx.x;
    int w = t >> 6, lane = t & 63;
    int col = lane & 15, quad = lane >> 4;
    int p0 = blockIdx.x * 64;
    int o0 = blockIdx.y * 64;
    int n = blockIdx.z;

    // stage X-tile: wave w stages rows w*16..w*16+15, 2 rows per GLDS
#pragma unroll
    for (int j = 0; j < 8; j++) {
        int rl = j * 2 + (lane >> 5);           // row within wave strip (local parity by lane)
        int row = w * 16 + rl;                  // row within tile; (row&7) == (rl&7)
        int slot = (lane & 31) ^ (rl & 7);      // xor applies to low 3 bits only
        GLDS(xt + ((size_t)n * HW + p0 + row) * 256 + slot * 8, Xs + (w * 16 + j * 2) * 256);
    }

    // A-frags direct from global (L2-resident, reused across p-blocks)
    const u16* wrow = Wb + (size_t)(o0 + w * 16 + col) * 256 + quad * 8;
    short8 A[8];
#pragma unroll
    for (int ks = 0; ks < 8; ks++) A[ks] = *(const short8*)(wrow + ks * 32);

    __syncthreads();

    f32x4 C[4];
#pragma unroll
    for (int pb = 0; pb < 4; pb++) C[pb] = (f32x4){0.f, 0.f, 0.f, 0.f};
    int c7 = col & 7;
#pragma unroll
    for (int pb = 0; pb < 4; pb++) {
        const u16* xr = Xs + (pb * 16 + col) * 256;
#pragma unroll
        for (int ks = 0; ks < 8; ks++) {
            int slot = (ks * 4 + quad) ^ c7;
            short8 Bf = *(const short8*)(xr + slot * 8);
            C[pb] = MFMA_K32(A[ks], Bf, C[pb]);
        }
    }

    int type = o0 >> 8;        // 0=q, 1=k, 2=v
    int h = (o0 >> 6) & 3;
    int nh = n * 4 + h;
    float sc = (type == 0) ? SCL : 1.0f;
    if (type == 2) {
        // V: [nh][d][p], d = w*16 + quad*4 + rg
#pragma unroll
        for (int rg = 0; rg < 4; rg++) {
            int d = w * 16 + quad * 4 + rg;
            float bias = bq[o0 + d];
            u16* vb = Vw + ((size_t)nh * 64 + d) * HW + p0 + col;
#pragma unroll
            for (int pb = 0; pb < 4; pb++)
                vb[pb * 16] = f2b(C[pb][rg] + bias);
        }
    } else {
        // Q/K: [nh][p][d], 4 contiguous d per lane -> 8B packed store
        u16* dst = (type == 0 ? Qw : Kw) + ((size_t)nh * HW + p0 + col) * 64 + w * 16 + quad * 4;
        float b0 = sc * bq[o0 + w * 16 + quad * 4 + 0];
        float b1 = sc * bq[o0 + w * 16 + quad * 4 + 1];
        float b2 = sc * bq[o0 + w * 16 + quad * 4 + 2];
        float b3 = sc * bq[o0 + w * 16 + quad * 4 + 3];
#pragma unroll
        for (int pb = 0; pb < 4; pb++) {
            uint2 o;
            o.x = (u32)f2b(C[pb][0] + b0) | ((u32)f2b(C[pb][1] + b1) << 16);
            o.y = (u32)f2b(C[pb][2] + b2) | ((u32)f2b(C[pb][3] + b3) << 16);
            *(uint2*)(dst + (size_t)(pb * 16) * 64) = o;
        }
    }
}

// ---------------- MFMA flash attention (transposed-S), epilogue -> bf16 attnT ----------------
__global__ __launch_bounds__(256) void flash_mfma(const u16* __restrict__ Qw, const u16* __restrict__ Kw,
                                                  const u16* __restrict__ Vw, u16* __restrict__ attnT) {
    __shared__ u16 Ks[2][4096];   // [j][d], 16B chunks xor-swizzled by row&7
    __shared__ u16 Vts[2][4096];  // [d][j], same swizzle
    int t = threadIdx.x;
    int w = t >> 6, lane = t & 63;
    int col = lane & 15, quad = lane >> 4;
    int q0 = blockIdx.x * 64;
    int nh = blockIdx.y;

    const u16* qp = Qw + ((size_t)nh * HW + q0 + w * 16 + col) * 64 + quad * 8;
    short8 qb0 = *(const short8*)qp;
    short8 qb1 = *(const short8*)(qp + 32);

    f32x4 Oac[4];
#pragma unroll
    for (int db = 0; db < 4; db++) Oac[db] = (f32x4){0.f, 0.f, 0.f, 0.f};
    float mI = -1e30f, lI = 0.f;

    const u16* kbase = Kw + (size_t)nh * HW * 64;  // [p][d]
    const u16* vbase = Vw + (size_t)nh * 64 * HW;  // [d][p]
    int lr = lane >> 3;
    int cc = lane & 7;
    int xo = (cc ^ lr) * 8;
    size_t kOff1 = (size_t)(w * 8 + lr) * 64 + xo;
    size_t kOff2 = (size_t)(w * 8 + lr + 32) * 64 + xo;
    size_t vOff1 = (size_t)(w * 8 + lr) * HW + xo;
    size_t vOff2 = (size_t)(w * 8 + lr + 32) * HW + xo;

#define STAGE(kt_, b_) do { \
        int kp_ = (kt_) * 64; \
        GLDS(kbase + (size_t)kp_ * 64 + kOff1, &Ks[b_][w * 512]); \
        GLDS(kbase + (size_t)kp_ * 64 + kOff2, &Ks[b_][w * 512 + 2048]); \
        GLDS(vbase + kp_ + vOff1, &Vts[b_][w * 512]); \
        GLDS(vbase + kp_ + vOff2, &Vts[b_][w * 512 + 2048]); \
    } while (0)

    STAGE(0, 0);
    __syncthreads();

    int c7 = col & 7;
    for (int kt = 0; kt < 64; kt++) {
        int cur = kt & 1;
        if (kt < 63) STAGE(kt + 1, cur ^ 1);
        const u16* KsC = Ks[cur];
        const u16* VtC = Vts[cur];

        f32x4 st[4];
#pragma unroll
        for (int jb = 0; jb < 4; jb++) {
            const u16* kr = KsC + (jb * 16 + col) * 64;
            short8 ka0 = *(const short8*)(kr + ((quad ^ c7) * 8));
            short8 ka1 = *(const short8*)(kr + (((quad + 4) ^ c7) * 8));
            f32x4 a = (f32x4){0.f, 0.f, 0.f, 0.f};
            a = MFMA_K32(ka0, qb0, a);
            a = MFMA_K32(ka1, qb1, a);
            st[jb] = a;
        }

        float tm = st[0][0];
#pragma unroll
        for (int jb = 0; jb < 4; jb++)
#pragma unroll
            for (int rg = 0; rg < 4; rg++) tm = fmaxf(tm, st[jb][rg]);
        tm = fmaxf(tm, __shfl_xor(tm, 16));
        tm = fmaxf(tm, __shfl_xor(tm, 32));
        float mnew = fmaxf(mI, tm);
        float al = __builtin_amdgcn_exp2f(mI - mnew);
        mI = mnew;
        float ps[4][4];
        float rsum = 0.f;
#pragma unroll
        for (int jb = 0; jb < 4; jb++)
#pragma unroll
            for (int rg = 0; rg < 4; rg++) {
                float p = __builtin_amdgcn_exp2f(st[jb][rg] - mnew);
                ps[jb][rg] = p;
                rsum += p;
            }
        rsum += __shfl_xor(rsum, 16);
        rsum += __shfl_xor(rsum, 32);
        lI = lI * al + rsum;

        short4v pt[4];
#pragma unroll
        for (int jb = 0; jb < 4; jb++)
#pragma unroll
            for (int rg = 0; rg < 4; rg++)
                pt[jb][rg] = (short)(__float_as_uint(ps[jb][rg]) >> 16);

#pragma unroll
        for (int db = 0; db < 4; db++) {
            Oac[db][0] *= al; Oac[db][1] *= al; Oac[db][2] *= al; Oac[db][3] *= al;
        }

#pragma unroll
        for (int db = 0; db < 4; db++) {
            const u16* vr = VtC + (db * 16 + col) * 64;
#pragma unroll
            for (int jb = 0; jb < 4; jb++) {
                int c = 2 * jb + (quad >> 1);
                short4v va = *(const short4v*)(vr + ((c ^ c7) * 8) + (quad & 1) * 4);
                Oac[db] = MFMA_K16(va, pt[jb], Oac[db]);
            }
        }
        __syncthreads();
    }
#undef STAGE

    // epilogue: attnT bf16 [n][q][c], c = h*64 + db*16 + quad*4 + rg -> packed 8B stores
    float rl = 1.0f / lI;
    u16* ab = attnT + ((size_t)(nh >> 2) * HW + q0 + w * 16 + col) * 256 + (nh & 3) * 64 + quad * 4;
#pragma unroll
    for (int db = 0; db < 4; db++) {
        uint2 o;
        o.x = (u32)f2b(Oac[db][0] * rl) | ((u32)f2b(Oac[db][1] * rl) << 16);
        o.y = (u32)f2b(Oac[db][2] * rl) | ((u32)f2b(Oac[db][3] * rl) << 16);
        *(uint2*)(ab + db * 16) = o;
    }
}

// ---------------- Proj MFMA GEMM + bias + residual + mask ----------------
// grid (64 p, 4 o, 4 n), block 256 (4 waves).
__global__ __launch_bounds__(256) void proj_mfma(const u16* __restrict__ attnT, const u16* __restrict__ Wpb,
                                                 const float* __restrict__ bp, const float* __restrict__ x,
                                                 const float* __restrict__ mask, float* __restrict__ out) {
    __shared__ u16 Xs[64 * 256];
    int t = threadIdx.x;
    int w = t >> 6, lane = t & 63;
    int col = lane & 15, quad = lane >> 4;
    int p0 = blockIdx.x * 64;
    int o0 = blockIdx.y * 64;
    int n = blockIdx.z;

#pragma unroll
    for (int j = 0; j < 8; j++) {
        int rl = j * 2 + (lane >> 5);
        int row = w * 16 + rl;
        int slot = (lane & 31) ^ (rl & 7);
        GLDS(attnT + ((size_t)n * HW + p0 + row) * 256 + slot * 8, Xs + (w * 16 + j * 2) * 256);
    }

    const u16* wrow = Wpb + (size_t)(o0 + w * 16 + col) * 256 + quad * 8;
    short8 A[8];
#pragma unroll
    for (int ks = 0; ks < 8; ks++) A[ks] = *(const short8*)(wrow + ks * 32);

    __syncthreads();

    f32x4 C[4];
#pragma unroll
    for (int pb = 0; pb < 4; pb++) C[pb] = (f32x4){0.f, 0.f, 0.f, 0.f};
    int c7 = col & 7;
#pragma unroll
    for (int pb = 0; pb < 4; pb++) {
        const u16* xr = Xs + (pb * 16 + col) * 256;
#pragma unroll
        for (int ks = 0; ks < 8; ks++) {
            int slot = (ks * 4 + quad) ^ c7;
            short8 Bf = *(const short8*)(xr + slot * 8);
            C[pb] = MFMA_K32(A[ks], Bf, C[pb]);
        }
    }

    // epilogue: out[(n*256+o)*HW + p] = (x + C + bp[o]) * mask[n][p]
#pragma unroll
    for (int rg = 0; rg < 4; rg++) {
        int o = o0 + w * 16 + quad * 4 + rg;
        float bias = bp[o];
        const float* xb = x + ((size_t)n * 256 + o) * HW + p0 + col;
        float* ob = out + ((size_t)n * 256 + o) * HW + p0 + col;
        const float* mb = mask + (size_t)n * HW + p0 + col;
#pragma unroll
        for (int pb = 0; pb < 4; pb++) {
            float mv = mb[pb * 16];
            ob[pb * 16] = (xb[pb * 16] + C[pb][rg] + bias) * mv;
        }
    }
}

// ---------------- mask passthrough ----------------
__global__ __launch_bounds__(256) void mask_copy(const float* __restrict__ mask, float* __restrict__ out) {
    int i = blockIdx.x * 256 + threadIdx.x;
    out[i] = mask[i];
}

extern "C" void kernel_launch(void* const* d_in, const int* in_sizes, int n_in,
                              void* d_out, int out_size, void* d_ws, size_t ws_size,
                              hipStream_t stream) {
    const float* x = (const float*)d_in[0];
    const float* mask = (const float*)d_in[1];
    const float* norm_w = (const float*)d_in[2];
    const float* norm_b = (const float*)d_in[3];
    const float* qkv_w = (const float*)d_in[4];
    const float* qkv_b = (const float*)d_in[5];
    const float* proj_w = (const float*)d_in[6];
    const float* proj_b = (const float*)d_in[7];
    float* out = (float*)d_out;

    float* ws = (float*)d_ws;
    float* stats = ws;                    // 64 f32
    float* pstats = ws + 64;              // 1024 f32
    u16* xt = (u16*)(ws + 2048);          // 4,194,304 u16
    u16* Qw = xt + 4194304;
    u16* Kw = Qw + 4194304;
    u16* Vw = Kw + 4194304;
    u16* attnT = Vw + 4194304;
    u16* Wqb = attnT + 4194304;           // 196,608 u16
    u16* Wpb = Wqb + 196608;              // 65,536 u16

    gn_partial<<<512, 256, 0, stream>>>(x, pstats);
    gn_final<<<1, 64, 0, stream>>>(pstats, stats);
    wconv<<<192, 256, 0, stream>>>(qkv_w, Wqb, 256);   // 768*256/4 threads
    wconv<<<64, 256, 0, stream>>>(proj_w, Wpb, 0);     // 256*256/4 threads
    gn_apply_t<<<dim3(64, 4, 4), 256, 0, stream>>>(x, norm_w, norm_b, stats, xt);
    qkv_mfma<<<dim3(64, 12, 4), 256, 0, stream>>>(xt, Wqb, qkv_b, Qw, Kw, Vw);
    flash_mfma<<<dim3(64, 16), 256, 0, stream>>>(Qw, Kw, Vw, attnT);
    proj_mfma<<<dim3(64, 4, 4), 256, 0, stream>>>(attnT, Wpb, proj_b, x, mask, out);
    mask_copy<<<64, 256, 0, stream>>>(mask, out + 4194304);
}

// Round 7
// 258.724 us; speedup vs baseline: 14.5698x; 1.1874x over previous
//
#include <hip/hip_runtime.h>

#define HW 4096
#define EPSV 1e-5f
#define SCL (0.125f * 1.44269504088896341f)   // 1/sqrt(64) * log2(e): softmax in exp2 domain

typedef unsigned short u16;
typedef unsigned int u32;
typedef __attribute__((ext_vector_type(8))) short short8;    // 8 bf16 (K=32 frag)
typedef __attribute__((ext_vector_type(4))) short short4v;   // 4 bf16 (K=16 frag)
typedef __attribute__((ext_vector_type(4))) float f32x4;     // C/D frag

#define MFMA_K32(a, b, c) __builtin_amdgcn_mfma_f32_16x16x32_bf16((a), (b), (c), 0, 0, 0)
#if __has_builtin(__builtin_amdgcn_mfma_f32_16x16x16bf16_1k)
#define MFMA_K16(a, b, c) __builtin_amdgcn_mfma_f32_16x16x16bf16_1k((a), (b), (c), 0, 0, 0)
#elif __has_builtin(__builtin_amdgcn_mfma_f32_16x16x16_bf16)
#define MFMA_K16(a, b, c) __builtin_amdgcn_mfma_f32_16x16x16_bf16((a), (b), (c), 0, 0, 0)
#else
// Host-pass parse stub only: the device pass selects a real builtin above.
#define MFMA_K16(a, b, c) (c)
#endif

#define GLDS(g, l) __builtin_amdgcn_global_load_lds( \
    (const __attribute__((address_space(1))) u16*)(g), \
    (__attribute__((address_space(3))) u16*)(l), 16, 0, 0)

__device__ __forceinline__ u16 f2b(float f) {
    u32 u = __float_as_uint(f);
    u32 r = (u + 0x7FFFu + ((u >> 16) & 1u)) >> 16;
    return (u16)r;
}

// ---------------- GroupNorm stage A: 512 blocks, partial sums ----------------
__global__ __launch_bounds__(256) void gn_partial(const float* __restrict__ x, float* __restrict__ ps) {
    int bid = blockIdx.x;
    const float4* base = (const float4*)x + (size_t)bid * 2048;
    int t = threadIdx.x;
    float s = 0.f, sq = 0.f;
    for (int i = t; i < 2048; i += 256) {
        float4 v = base[i];
        s += v.x + v.y + v.z + v.w;
        sq += v.x * v.x + v.y * v.y + v.z * v.z + v.w * v.w;
    }
    __shared__ float rs[256], rq[256];
    rs[t] = s; rq[t] = sq;
    __syncthreads();
    for (int o = 128; o > 0; o >>= 1) {
        if (t < o) { rs[t] += rs[t + o]; rq[t] += rq[t + o]; }
        __syncthreads();
    }
    if (t == 0) { ps[2 * bid] = rs[0]; ps[2 * bid + 1] = rq[0]; }
}

// ---------------- GroupNorm stage B: finalize 32 groups ----------------
__global__ __launch_bounds__(64) void gn_final(const float* __restrict__ ps, float* __restrict__ stats) {
    int t = threadIdx.x;
    if (t < 32) {
        float s = 0.f, sq = 0.f;
        for (int i = 0; i < 16; i++) {
            s += ps[2 * (t * 16 + i)];
            sq += ps[2 * (t * 16 + i) + 1];
        }
        float mean = s * (1.f / 131072.f);
        float var = sq * (1.f / 131072.f) - mean * mean;
        stats[t] = mean;
        stats[32 + t] = rsqrtf(var + EPSV);
    }
}

// ---------------- weight fp32 -> bf16 (rows < nscaled get * SCL) ----------------
__global__ __launch_bounds__(256) void wconv(const float* __restrict__ src, u16* __restrict__ dst, int nscaled) {
    int idx = blockIdx.x * 256 + threadIdx.x;
    int row = idx >> 6;
    float sc = (row < nscaled) ? SCL : 1.0f;
    float4 v = *((const float4*)src + idx);
    u32 lo = (u32)f2b(v.x * sc) | ((u32)f2b(v.y * sc) << 16);
    u32 hi = (u32)f2b(v.z * sc) | ((u32)f2b(v.w * sc) << 16);
    uint2 o; o.x = lo; o.y = hi;
    *(uint2*)(dst + (size_t)idx * 4) = o;
}

// ---------------- GroupNorm apply + transpose -> bf16 xt[n][p][c] ----------------
__global__ __launch_bounds__(256) void gn_apply_t(const float* __restrict__ x, const float* __restrict__ w,
                                                  const float* __restrict__ b, const float* __restrict__ stats,
                                                  u16* __restrict__ xt) {
    __shared__ u16 Tt[64][72];
    int t = threadIdx.x;
    int p0 = blockIdx.x * 64;
    int c0 = blockIdx.y * 64;
    int n = blockIdx.z;
    int pc = (t & 15) * 4;
#pragma unroll
    for (int jj = 0; jj < 4; jj++) {
        int r = (t >> 4) + jj * 16;
        int c = c0 + r;
        int grp = n * 8 + (c >> 5);
        float mean = stats[grp], rstd = stats[32 + grp];
        float a = rstd * w[c];
        float bb = b[c] - mean * a;
        float4 v = *(const float4*)(x + ((size_t)n * 256 + c) * HW + p0 + pc);
        Tt[pc + 0][r] = f2b(v.x * a + bb);
        Tt[pc + 1][r] = f2b(v.y * a + bb);
        Tt[pc + 2][r] = f2b(v.z * a + bb);
        Tt[pc + 3][r] = f2b(v.w * a + bb);
    }
    __syncthreads();
    int p = t >> 2, ck = t & 3;
    short8 s0 = *(const short8*)&Tt[p][ck * 16];
    short8 s1 = *(const short8*)&Tt[p][ck * 16 + 8];
    u16* dst = xt + ((size_t)n * HW + p0 + p) * 256 + c0 + ck * 16;
    *(short8*)dst = s0;
    *(short8*)(dst + 8) = s1;
}

// ---------------- QKV MFMA GEMM ----------------
__global__ __launch_bounds__(256) void qkv_mfma(const u16* __restrict__ xt, const u16* __restrict__ Wb,
                                                const float* __restrict__ bq, u16* __restrict__ Qw,
                                                u16* __restrict__ Kw, u16* __restrict__ Vw) {
    __shared__ u16 Xs[64 * 256];   // [p][c], chunk c/8 xor-swizzled by p&7
    int t = threadIdx.x;
    int w = t >> 6, lane = t & 63;
    int col = lane & 15, quad = lane >> 4;
    int p0 = blockIdx.x * 64;
    int o0 = blockIdx.y * 64;
    int n = blockIdx.z;

#pragma unroll
    for (int j = 0; j < 8; j++) {
        int rl = j * 2 + (lane >> 5);
        int row = w * 16 + rl;
        int slot = (lane & 31) ^ (rl & 7);
        GLDS(xt + ((size_t)n * HW + p0 + row) * 256 + slot * 8, Xs + (w * 16 + j * 2) * 256);
    }

    const u16* wrow = Wb + (size_t)(o0 + w * 16 + col) * 256 + quad * 8;
    short8 A[8];
#pragma unroll
    for (int ks = 0; ks < 8; ks++) A[ks] = *(const short8*)(wrow + ks * 32);

    __syncthreads();

    f32x4 C[4];
#pragma unroll
    for (int pb = 0; pb < 4; pb++) C[pb] = (f32x4){0.f, 0.f, 0.f, 0.f};
    int c7 = col & 7;
#pragma unroll
    for (int pb = 0; pb < 4; pb++) {
        const u16* xr = Xs + (pb * 16 + col) * 256;
#pragma unroll
        for (int ks = 0; ks < 8; ks++) {
            int slot = (ks * 4 + quad) ^ c7;
            short8 Bf = *(const short8*)(xr + slot * 8);
            C[pb] = MFMA_K32(A[ks], Bf, C[pb]);
        }
    }

    int type = o0 >> 8;
    int h = (o0 >> 6) & 3;
    int nh = n * 4 + h;
    float sc = (type == 0) ? SCL : 1.0f;
    if (type == 2) {
#pragma unroll
        for (int rg = 0; rg < 4; rg++) {
            int d = w * 16 + quad * 4 + rg;
            float bias = bq[o0 + d];
            u16* vb = Vw + ((size_t)nh * 64 + d) * HW + p0 + col;
#pragma unroll
            for (int pb = 0; pb < 4; pb++)
                vb[pb * 16] = f2b(C[pb][rg] + bias);
        }
    } else {
        u16* dst = (type == 0 ? Qw : Kw) + ((size_t)nh * HW + p0 + col) * 64 + w * 16 + quad * 4;
        float b0 = sc * bq[o0 + w * 16 + quad * 4 + 0];
        float b1 = sc * bq[o0 + w * 16 + quad * 4 + 1];
        float b2 = sc * bq[o0 + w * 16 + quad * 4 + 2];
        float b3 = sc * bq[o0 + w * 16 + quad * 4 + 3];
#pragma unroll
        for (int pb = 0; pb < 4; pb++) {
            uint2 o;
            o.x = (u32)f2b(C[pb][0] + b0) | ((u32)f2b(C[pb][1] + b1) << 16);
            o.y = (u32)f2b(C[pb][2] + b2) | ((u32)f2b(C[pb][3] + b3) << 16);
            *(uint2*)(dst + (size_t)(pb * 16) * 64) = o;
        }
    }
}

// ---------------- MFMA flash attention v3: 32 q per wave (two groups, shared K/V frags) ----------------
// grid (32 q-tiles of 128, 16 nh), block 256 (4 waves). Wave w: q-cols q0+w*32..+31.
// K/V fragments read once per tile feed both q-groups; two independent softmax chains (ILP-2).
__global__ __launch_bounds__(256) void flash_mfma(const u16* __restrict__ Qw, const u16* __restrict__ Kw,
                                                  const u16* __restrict__ Vw, u16* __restrict__ attnT) {
    __shared__ u16 Ks[2][4096];   // [j][d], 16B chunks xor-swizzled by row&7
    __shared__ u16 Vts[2][4096];  // [d][j], same swizzle
    int t = threadIdx.x;
    int w = t >> 6, lane = t & 63;
    int col = lane & 15, quad = lane >> 4;
    int q0 = blockIdx.x * 128;
    int nh = blockIdx.y;

    // Q fragments for both groups: qA = q0+w*32+col, qB = qA+16
    const u16* qp = Qw + ((size_t)nh * HW + q0 + w * 32 + col) * 64 + quad * 8;
    short8 qa0 = *(const short8*)qp;
    short8 qa1 = *(const short8*)(qp + 32);
    short8 qc0 = *(const short8*)(qp + 1024);        // +16 rows * 64
    short8 qc1 = *(const short8*)(qp + 1024 + 32);

    f32x4 OaA[4], OaB[4];
#pragma unroll
    for (int db = 0; db < 4; db++) {
        OaA[db] = (f32x4){0.f, 0.f, 0.f, 0.f};
        OaB[db] = (f32x4){0.f, 0.f, 0.f, 0.f};
    }
    float mA = -1e30f, lA = 0.f, mB = -1e30f, lB = 0.f;

    const u16* kbase = Kw + (size_t)nh * HW * 64;  // [p][d]
    const u16* vbase = Vw + (size_t)nh * 64 * HW;  // [d][p]
    int lr = lane >> 3;
    int cc = lane & 7;
    int xo = (cc ^ lr) * 8;
    size_t kOff1 = (size_t)(w * 8 + lr) * 64 + xo;
    size_t kOff2 = (size_t)(w * 8 + lr + 32) * 64 + xo;
    size_t vOff1 = (size_t)(w * 8 + lr) * HW + xo;
    size_t vOff2 = (size_t)(w * 8 + lr + 32) * HW + xo;

#define STAGE(kt_, b_) do { \
        int kp_ = (kt_) * 64; \
        GLDS(kbase + (size_t)kp_ * 64 + kOff1, &Ks[b_][w * 512]); \
        GLDS(kbase + (size_t)kp_ * 64 + kOff2, &Ks[b_][w * 512 + 2048]); \
        GLDS(vbase + kp_ + vOff1, &Vts[b_][w * 512]); \
        GLDS(vbase + kp_ + vOff2, &Vts[b_][w * 512 + 2048]); \
    } while (0)

    STAGE(0, 0);
    __syncthreads();

    int c7 = col & 7;
    for (int kt = 0; kt < 64; kt++) {
        int cur = kt & 1;
        if (kt < 63) STAGE(kt + 1, cur ^ 1);
        const u16* KsC = Ks[cur];
        const u16* VtC = Vts[cur];

        // S^T for both q-groups; K-frags read once
        f32x4 sA[4], sB[4];
#pragma unroll
        for (int jb = 0; jb < 4; jb++) {
            const u16* kr = KsC + (jb * 16 + col) * 64;
            short8 ka0 = *(const short8*)(kr + ((quad ^ c7) * 8));
            short8 ka1 = *(const short8*)(kr + (((quad + 4) ^ c7) * 8));
            f32x4 a = (f32x4){0.f, 0.f, 0.f, 0.f};
            a = MFMA_K32(ka0, qa0, a);
            a = MFMA_K32(ka1, qa1, a);
            sA[jb] = a;
            f32x4 b = (f32x4){0.f, 0.f, 0.f, 0.f};
            b = MFMA_K32(ka0, qc0, b);
            b = MFMA_K32(ka1, qc1, b);
            sB[jb] = b;
        }

        // two independent softmax chains (ILP)
        float tmA = sA[0][0], tmB = sB[0][0];
#pragma unroll
        for (int jb = 0; jb < 4; jb++)
#pragma unroll
            for (int rg = 0; rg < 4; rg++) {
                tmA = fmaxf(tmA, sA[jb][rg]);
                tmB = fmaxf(tmB, sB[jb][rg]);
            }
        tmA = fmaxf(tmA, __shfl_xor(tmA, 16));
        tmB = fmaxf(tmB, __shfl_xor(tmB, 16));
        tmA = fmaxf(tmA, __shfl_xor(tmA, 32));
        tmB = fmaxf(tmB, __shfl_xor(tmB, 32));
        float mnA = fmaxf(mA, tmA), mnB = fmaxf(mB, tmB);
        float alA = __builtin_amdgcn_exp2f(mA - mnA);
        float alB = __builtin_amdgcn_exp2f(mB - mnB);
        mA = mnA; mB = mnB;
        float rsA = 0.f, rsB = 0.f;
#pragma unroll
        for (int jb = 0; jb < 4; jb++)
#pragma unroll
            for (int rg = 0; rg < 4; rg++) {
                float pa = __builtin_amdgcn_exp2f(sA[jb][rg] - mnA);
                float pb = __builtin_amdgcn_exp2f(sB[jb][rg] - mnB);
                sA[jb][rg] = pa; sB[jb][rg] = pb;
                rsA += pa; rsB += pb;
            }
        rsA += __shfl_xor(rsA, 16);
        rsB += __shfl_xor(rsB, 16);
        rsA += __shfl_xor(rsA, 32);
        rsB += __shfl_xor(rsB, 32);
        lA = lA * alA + rsA;
        lB = lB * alB + rsB;

        // P^T B-frags (K16 layout: k = quad*4 + rg), truncate to bf16
        short4v ptA[4], ptB[4];
#pragma unroll
        for (int jb = 0; jb < 4; jb++)
#pragma unroll
            for (int rg = 0; rg < 4; rg++) {
                ptA[jb][rg] = (short)(__float_as_uint(sA[jb][rg]) >> 16);
                ptB[jb][rg] = (short)(__float_as_uint(sB[jb][rg]) >> 16);
            }

#pragma unroll
        for (int db = 0; db < 4; db++) {
            OaA[db][0] *= alA; OaA[db][1] *= alA; OaA[db][2] *= alA; OaA[db][3] *= alA;
            OaB[db][0] *= alB; OaB[db][1] *= alB; OaB[db][2] *= alB; OaB[db][3] *= alB;
        }

        // O^T += V^T · P^T; V-frags read once per (db,jb)
#pragma unroll
        for (int db = 0; db < 4; db++) {
            const u16* vr = VtC + (db * 16 + col) * 64;
#pragma unroll
            for (int jb = 0; jb < 4; jb++) {
                int c = 2 * jb + (quad >> 1);
                short4v va = *(const short4v*)(vr + ((c ^ c7) * 8) + (quad & 1) * 4);
                OaA[db] = MFMA_K16(va, ptA[jb], OaA[db]);
                OaB[db] = MFMA_K16(va, ptB[jb], OaB[db]);
            }
        }
        __syncthreads();
    }
#undef STAGE

    // epilogue: attnT bf16 [n][q][c], c = h*64 + db*16 + quad*4 + rg -> packed 8B stores
    float rlA = 1.0f / lA, rlB = 1.0f / lB;
    u16* abA = attnT + ((size_t)(nh >> 2) * HW + q0 + w * 32 + col) * 256 + (nh & 3) * 64 + quad * 4;
    u16* abB = abA + 16 * 256;
#pragma unroll
    for (int db = 0; db < 4; db++) {
        uint2 oA, oB;
        oA.x = (u32)f2b(OaA[db][0] * rlA) | ((u32)f2b(OaA[db][1] * rlA) << 16);
        oA.y = (u32)f2b(OaA[db][2] * rlA) | ((u32)f2b(OaA[db][3] * rlA) << 16);
        oB.x = (u32)f2b(OaB[db][0] * rlB) | ((u32)f2b(OaB[db][1] * rlB) << 16);
        oB.y = (u32)f2b(OaB[db][2] * rlB) | ((u32)f2b(OaB[db][3] * rlB) << 16);
        *(uint2*)(abA + db * 16) = oA;
        *(uint2*)(abB + db * 16) = oB;
    }
}

// ---------------- Proj MFMA GEMM + bias + residual + mask ----------------
__global__ __launch_bounds__(256) void proj_mfma(const u16* __restrict__ attnT, const u16* __restrict__ Wpb,
                                                 const float* __restrict__ bp, const float* __restrict__ x,
                                                 const float* __restrict__ mask, float* __restrict__ out) {
    __shared__ u16 Xs[64 * 256];
    int t = threadIdx.x;
    int w = t >> 6, lane = t & 63;
    int col = lane & 15, quad = lane >> 4;
    int p0 = blockIdx.x * 64;
    int o0 = blockIdx.y * 64;
    int n = blockIdx.z;

#pragma unroll
    for (int j = 0; j < 8; j++) {
        int rl = j * 2 + (lane >> 5);
        int row = w * 16 + rl;
        int slot = (lane & 31) ^ (rl & 7);
        GLDS(attnT + ((size_t)n * HW + p0 + row) * 256 + slot * 8, Xs + (w * 16 + j * 2) * 256);
    }

    const u16* wrow = Wpb + (size_t)(o0 + w * 16 + col) * 256 + quad * 8;
    short8 A[8];
#pragma unroll
    for (int ks = 0; ks < 8; ks++) A[ks] = *(const short8*)(wrow + ks * 32);

    __syncthreads();

    f32x4 C[4];
#pragma unroll
    for (int pb = 0; pb < 4; pb++) C[pb] = (f32x4){0.f, 0.f, 0.f, 0.f};
    int c7 = col & 7;
#pragma unroll
    for (int pb = 0; pb < 4; pb++) {
        const u16* xr = Xs + (pb * 16 + col) * 256;
#pragma unroll
        for (int ks = 0; ks < 8; ks++) {
            int slot = (ks * 4 + quad) ^ c7;
            short8 Bf = *(const short8*)(xr + slot * 8);
            C[pb] = MFMA_K32(A[ks], Bf, C[pb]);
        }
    }

#pragma unroll
    for (int rg = 0; rg < 4; rg++) {
        int o = o0 + w * 16 + quad * 4 + rg;
        float bias = bp[o];
        const float* xb = x + ((size_t)n * 256 + o) * HW + p0 + col;
        float* ob = out + ((size_t)n * 256 + o) * HW + p0 + col;
        const float* mb = mask + (size_t)n * HW + p0 + col;
#pragma unroll
        for (int pb = 0; pb < 4; pb++) {
            float mv = mb[pb * 16];
            ob[pb * 16] = (xb[pb * 16] + C[pb][rg] + bias) * mv;
        }
    }
}

// ---------------- mask passthrough ----------------
__global__ __launch_bounds__(256) void mask_copy(const float* __restrict__ mask, float* __restrict__ out) {
    int i = blockIdx.x * 256 + threadIdx.x;
    out[i] = mask[i];
}

extern "C" void kernel_launch(void* const* d_in, const int* in_sizes, int n_in,
                              void* d_out, int out_size, void* d_ws, size_t ws_size,
                              hipStream_t stream) {
    const float* x = (const float*)d_in[0];
    const float* mask = (const float*)d_in[1];
    const float* norm_w = (const float*)d_in[2];
    const float* norm_b = (const float*)d_in[3];
    const float* qkv_w = (const float*)d_in[4];
    const float* qkv_b = (const float*)d_in[5];
    const float* proj_w = (const float*)d_in[6];
    const float* proj_b = (const float*)d_in[7];
    float* out = (float*)d_out;

    float* ws = (float*)d_ws;
    float* stats = ws;                    // 64 f32
    float* pstats = ws + 64;              // 1024 f32
    u16* xt = (u16*)(ws + 2048);          // 4,194,304 u16
    u16* Qw = xt + 4194304;
    u16* Kw = Qw + 4194304;
    u16* Vw = Kw + 4194304;
    u16* attnT = Vw + 4194304;
    u16* Wqb = attnT + 4194304;           // 196,608 u16
    u16* Wpb = Wqb + 196608;              // 65,536 u16

    gn_partial<<<512, 256, 0, stream>>>(x, pstats);
    gn_final<<<1, 64, 0, stream>>>(pstats, stats);
    wconv<<<192, 256, 0, stream>>>(qkv_w, Wqb, 256);   // 768*256/4 threads
    wconv<<<64, 256, 0, stream>>>(proj_w, Wpb, 0);     // 256*256/4 threads
    gn_apply_t<<<dim3(64, 4, 4), 256, 0, stream>>>(x, norm_w, norm_b, stats, xt);
    qkv_mfma<<<dim3(64, 12, 4), 256, 0, stream>>>(xt, Wqb, qkv_b, Qw, Kw, Vw);
    flash_mfma<<<dim3(32, 16), 256, 0, stream>>>(Qw, Kw, Vw, attnT);
    proj_mfma<<<dim3(64, 4, 4), 256, 0, stream>>>(attnT, Wpb, proj_b, x, mask, out);
    mask_copy<<<64, 256, 0, stream>>>(mask, out + 4194304);
}

// Round 8
// 247.338 us; speedup vs baseline: 15.2405x; 1.0460x over previous
//
#include <hip/hip_runtime.h>

#define HW 4096
#define EPSV 1e-5f
#define SCL (0.125f * 1.44269504088896341f)   // 1/sqrt(64) * log2(e): softmax in exp2 domain

typedef unsigned short u16;
typedef unsigned int u32;
typedef __attribute__((ext_vector_type(8))) short short8;    // 8 bf16 (K=32 frag)
typedef __attribute__((ext_vector_type(4))) short short4v;   // 4 bf16 (K=16 frag)
typedef __attribute__((ext_vector_type(4))) float f32x4;     // C/D frag

#define MFMA_K32(a, b, c) __builtin_amdgcn_mfma_f32_16x16x32_bf16((a), (b), (c), 0, 0, 0)
#if __has_builtin(__builtin_amdgcn_mfma_f32_16x16x16bf16_1k)
#define MFMA_K16(a, b, c) __builtin_amdgcn_mfma_f32_16x16x16bf16_1k((a), (b), (c), 0, 0, 0)
#elif __has_builtin(__builtin_amdgcn_mfma_f32_16x16x16_bf16)
#define MFMA_K16(a, b, c) __builtin_amdgcn_mfma_f32_16x16x16_bf16((a), (b), (c), 0, 0, 0)
#else
// Host-pass parse stub only: the device pass selects a real builtin above.
#define MFMA_K16(a, b, c) (c)
#endif

#define GLDS(g, l) __builtin_amdgcn_global_load_lds( \
    (const __attribute__((address_space(1))) u16*)(g), \
    (__attribute__((address_space(3))) u16*)(l), 16, 0, 0)

__device__ __forceinline__ u16 f2b(float f) {
    u32 u = __float_as_uint(f);
    u32 r = (u + 0x7FFFu + ((u >> 16) & 1u)) >> 16;
    return (u16)r;
}

// ---------------- GroupNorm stage A: 512 blocks, partial sums ----------------
__global__ __launch_bounds__(256) void gn_partial(const float* __restrict__ x, float* __restrict__ ps) {
    int bid = blockIdx.x;
    const float4* base = (const float4*)x + (size_t)bid * 2048;
    int t = threadIdx.x;
    float s = 0.f, sq = 0.f;
    for (int i = t; i < 2048; i += 256) {
        float4 v = base[i];
        s += v.x + v.y + v.z + v.w;
        sq += v.x * v.x + v.y * v.y + v.z * v.z + v.w * v.w;
    }
    __shared__ float rs[256], rq[256];
    rs[t] = s; rq[t] = sq;
    __syncthreads();
    for (int o = 128; o > 0; o >>= 1) {
        if (t < o) { rs[t] += rs[t + o]; rq[t] += rq[t + o]; }
        __syncthreads();
    }
    if (t == 0) { ps[2 * bid] = rs[0]; ps[2 * bid + 1] = rq[0]; }
}

// ---------------- GroupNorm stage B: finalize 32 groups ----------------
__global__ __launch_bounds__(64) void gn_final(const float* __restrict__ ps, float* __restrict__ stats) {
    int t = threadIdx.x;
    if (t < 32) {
        float s = 0.f, sq = 0.f;
        for (int i = 0; i < 16; i++) {
            s += ps[2 * (t * 16 + i)];
            sq += ps[2 * (t * 16 + i) + 1];
        }
        float mean = s * (1.f / 131072.f);
        float var = sq * (1.f / 131072.f) - mean * mean;
        stats[t] = mean;
        stats[32 + t] = rsqrtf(var + EPSV);
    }
}

// ---------------- weight fp32 -> bf16 (rows < nscaled get * SCL) ----------------
__global__ __launch_bounds__(256) void wconv(const float* __restrict__ src, u16* __restrict__ dst, int nscaled) {
    int idx = blockIdx.x * 256 + threadIdx.x;
    int row = idx >> 6;
    float sc = (row < nscaled) ? SCL : 1.0f;
    float4 v = *((const float4*)src + idx);
    u32 lo = (u32)f2b(v.x * sc) | ((u32)f2b(v.y * sc) << 16);
    u32 hi = (u32)f2b(v.z * sc) | ((u32)f2b(v.w * sc) << 16);
    uint2 o; o.x = lo; o.y = hi;
    *(uint2*)(dst + (size_t)idx * 4) = o;
}

// ---------------- GroupNorm apply + transpose -> bf16 xt[n][p][c] ----------------
__global__ __launch_bounds__(256) void gn_apply_t(const float* __restrict__ x, const float* __restrict__ w,
                                                  const float* __restrict__ b, const float* __restrict__ stats,
                                                  u16* __restrict__ xt) {
    __shared__ u16 Tt[64][72];
    int t = threadIdx.x;
    int p0 = blockIdx.x * 64;
    int c0 = blockIdx.y * 64;
    int n = blockIdx.z;
    int pc = (t & 15) * 4;
#pragma unroll
    for (int jj = 0; jj < 4; jj++) {
        int r = (t >> 4) + jj * 16;
        int c = c0 + r;
        int grp = n * 8 + (c >> 5);
        float mean = stats[grp], rstd = stats[32 + grp];
        float a = rstd * w[c];
        float bb = b[c] - mean * a;
        float4 v = *(const float4*)(x + ((size_t)n * 256 + c) * HW + p0 + pc);
        Tt[pc + 0][r] = f2b(v.x * a + bb);
        Tt[pc + 1][r] = f2b(v.y * a + bb);
        Tt[pc + 2][r] = f2b(v.z * a + bb);
        Tt[pc + 3][r] = f2b(v.w * a + bb);
    }
    __syncthreads();
    int p = t >> 2, ck = t & 3;
    short8 s0 = *(const short8*)&Tt[p][ck * 16];
    short8 s1 = *(const short8*)&Tt[p][ck * 16 + 8];
    u16* dst = xt + ((size_t)n * HW + p0 + p) * 256 + c0 + ck * 16;
    *(short8*)dst = s0;
    *(short8*)(dst + 8) = s1;
}

// ---------------- QKV MFMA GEMM ----------------
__global__ __launch_bounds__(256) void qkv_mfma(const u16* __restrict__ xt, const u16* __restrict__ Wb,
                                                const float* __restrict__ bq, u16* __restrict__ Qw,
                                                u16* __restrict__ Kw, u16* __restrict__ Vw) {
    __shared__ u16 Xs[64 * 256];   // [p][c], chunk c/8 xor-swizzled by p&7
    int t = threadIdx.x;
    int w = t >> 6, lane = t & 63;
    int col = lane & 15, quad = lane >> 4;
    int p0 = blockIdx.x * 64;
    int o0 = blockIdx.y * 64;
    int n = blockIdx.z;

#pragma unroll
    for (int j = 0; j < 8; j++) {
        int rl = j * 2 + (lane >> 5);
        int row = w * 16 + rl;
        int slot = (lane & 31) ^ (rl & 7);
        GLDS(xt + ((size_t)n * HW + p0 + row) * 256 + slot * 8, Xs + (w * 16 + j * 2) * 256);
    }

    const u16* wrow = Wb + (size_t)(o0 + w * 16 + col) * 256 + quad * 8;
    short8 A[8];
#pragma unroll
    for (int ks = 0; ks < 8; ks++) A[ks] = *(const short8*)(wrow + ks * 32);

    __syncthreads();

    f32x4 C[4];
#pragma unroll
    for (int pb = 0; pb < 4; pb++) C[pb] = (f32x4){0.f, 0.f, 0.f, 0.f};
    int c7 = col & 7;
#pragma unroll
    for (int pb = 0; pb < 4; pb++) {
        const u16* xr = Xs + (pb * 16 + col) * 256;
#pragma unroll
        for (int ks = 0; ks < 8; ks++) {
            int slot = (ks * 4 + quad) ^ c7;
            short8 Bf = *(const short8*)(xr + slot * 8);
            C[pb] = MFMA_K32(A[ks], Bf, C[pb]);
        }
    }

    int type = o0 >> 8;
    int h = (o0 >> 6) & 3;
    int nh = n * 4 + h;
    float sc = (type == 0) ? SCL : 1.0f;
    if (type == 2) {
#pragma unroll
        for (int rg = 0; rg < 4; rg++) {
            int d = w * 16 + quad * 4 + rg;
            float bias = bq[o0 + d];
            u16* vb = Vw + ((size_t)nh * 64 + d) * HW + p0 + col;
#pragma unroll
            for (int pb = 0; pb < 4; pb++)
                vb[pb * 16] = f2b(C[pb][rg] + bias);
        }
    } else {
        u16* dst = (type == 0 ? Qw : Kw) + ((size_t)nh * HW + p0 + col) * 64 + w * 16 + quad * 4;
        float b0 = sc * bq[o0 + w * 16 + quad * 4 + 0];
        float b1 = sc * bq[o0 + w * 16 + quad * 4 + 1];
        float b2 = sc * bq[o0 + w * 16 + quad * 4 + 2];
        float b3 = sc * bq[o0 + w * 16 + quad * 4 + 3];
#pragma unroll
        for (int pb = 0; pb < 4; pb++) {
            uint2 o;
            o.x = (u32)f2b(C[pb][0] + b0) | ((u32)f2b(C[pb][1] + b1) << 16);
            o.y = (u32)f2b(C[pb][2] + b2) | ((u32)f2b(C[pb][3] + b3) << 16);
            *(uint2*)(dst + (size_t)(pb * 16) * 64) = o;
        }
    }
}

// ---------------- MFMA flash attention v4: 32 q per wave, j-tile 128 ----------------
// grid (32 q-tiles of 128, 16 nh), block 256 (4 waves). 32 steps of 128 j.
// Halves the number of serial softmax chains and barriers vs j-tile 64.
// l-reduction across quads deferred to epilogue (only m needs per-step cross-lane consistency).
__global__ __launch_bounds__(256) void flash_mfma(const u16* __restrict__ Qw, const u16* __restrict__ Kw,
                                                  const u16* __restrict__ Vw, u16* __restrict__ attnT) {
    __shared__ u16 Ks[2][128 * 64];   // [j][d], 16B chunks xor-swizzled by j&7
    __shared__ u16 Vts[2][64 * 128];  // [d][j], 16B chunks xor-swizzled by d&7
    int t = threadIdx.x;
    int w = t >> 6, lane = t & 63;
    int col = lane & 15, quad = lane >> 4;
    int q0 = blockIdx.x * 128;
    int nh = blockIdx.y;

    // Q fragments for both groups: qA = q0+w*32+col, qB = qA+16
    const u16* qp = Qw + ((size_t)nh * HW + q0 + w * 32 + col) * 64 + quad * 8;
    short8 qa0 = *(const short8*)qp;
    short8 qa1 = *(const short8*)(qp + 32);
    short8 qc0 = *(const short8*)(qp + 1024);
    short8 qc1 = *(const short8*)(qp + 1024 + 32);

    f32x4 OaA[4], OaB[4];
#pragma unroll
    for (int db = 0; db < 4; db++) {
        OaA[db] = (f32x4){0.f, 0.f, 0.f, 0.f};
        OaB[db] = (f32x4){0.f, 0.f, 0.f, 0.f};
    }
    float mA = -1e30f, lA = 0.f, mB = -1e30f, lB = 0.f;  // l: per-lane partial

    const u16* kbase = Kw + (size_t)nh * HW * 64;  // [p][d]
    const u16* vbase = Vw + (size_t)nh * 64 * HW;  // [d][p]
    // K staging: 8 rows/GLDS; wave w rows w*8 + s*32, s=0..3
    int lrK = lane >> 3;           // 0..7
    int ccK = lane & 7;
    size_t kSrc = (size_t)(w * 8 + lrK) * 64 + (ccK ^ lrK) * 8;  // + s*32*64 + j0*64
    // V staging: 4 rows/GLDS; wave w rows w*16 + m*4 + rv, m=0..3
    int rvV = lane >> 4;           // 0..3
    int cvV = lane & 15;

#define STAGE(jt_, b_) do { \
        int j0_ = (jt_) * 128; \
        _Pragma("unroll") \
        for (int s_ = 0; s_ < 4; s_++) \
            GLDS(kbase + (size_t)j0_ * 64 + kSrc + (size_t)(s_ * 32) * 64, &Ks[b_][(w * 8 + s_ * 32) * 64]); \
        _Pragma("unroll") \
        for (int m_ = 0; m_ < 4; m_++) { \
            int d_ = w * 16 + m_ * 4 + rvV; \
            GLDS(vbase + (size_t)d_ * HW + j0_ + ((cvV ^ (d_ & 7)) * 8), &Vts[b_][(w * 16 + m_ * 4) * 128]); \
        } \
    } while (0)

    STAGE(0, 0);
    __syncthreads();

    int c7 = col & 7;
    for (int jt = 0; jt < 32; jt++) {
        int cur = jt & 1;
        if (jt < 31) STAGE(jt + 1, cur ^ 1);
        const u16* KsC = Ks[cur];
        const u16* VtC = Vts[cur];

        // S^T for both q-groups; K-frags read once (8 jb of 16 j)
        f32x4 sA[8], sB[8];
#pragma unroll
        for (int jb = 0; jb < 8; jb++) {
            const u16* kr = KsC + (jb * 16 + col) * 64;
            short8 ka0 = *(const short8*)(kr + ((quad ^ c7) * 8));
            short8 ka1 = *(const short8*)(kr + (((quad + 4) ^ c7) * 8));
            f32x4 a = (f32x4){0.f, 0.f, 0.f, 0.f};
            a = MFMA_K32(ka0, qa0, a);
            a = MFMA_K32(ka1, qa1, a);
            sA[jb] = a;
            f32x4 b = (f32x4){0.f, 0.f, 0.f, 0.f};
            b = MFMA_K32(ka0, qc0, b);
            b = MFMA_K32(ka1, qc1, b);
            sB[jb] = b;
        }

        // two independent softmax chains; only max needs cross-quad shuffles
        float tmA = sA[0][0], tmB = sB[0][0];
#pragma unroll
        for (int jb = 0; jb < 8; jb++)
#pragma unroll
            for (int rg = 0; rg < 4; rg++) {
                tmA = fmaxf(tmA, sA[jb][rg]);
                tmB = fmaxf(tmB, sB[jb][rg]);
            }
        tmA = fmaxf(tmA, __shfl_xor(tmA, 16));
        tmB = fmaxf(tmB, __shfl_xor(tmB, 16));
        tmA = fmaxf(tmA, __shfl_xor(tmA, 32));
        tmB = fmaxf(tmB, __shfl_xor(tmB, 32));
        float mnA = fmaxf(mA, tmA), mnB = fmaxf(mB, tmB);
        float alA = __builtin_amdgcn_exp2f(mA - mnA);
        float alB = __builtin_amdgcn_exp2f(mB - mnB);
        mA = mnA; mB = mnB;

        // exp2 + pack per jb (frees score regs as we go); l per-lane partial
        short4v ptA[8], ptB[8];
        float lpA = 0.f, lpB = 0.f;
#pragma unroll
        for (int jb = 0; jb < 8; jb++) {
#pragma unroll
            for (int rg = 0; rg < 4; rg++) {
                float pa = __builtin_amdgcn_exp2f(sA[jb][rg] - mnA);
                float pb = __builtin_amdgcn_exp2f(sB[jb][rg] - mnB);
                lpA += pa; lpB += pb;
                ptA[jb][rg] = (short)(__float_as_uint(pa) >> 16);
                ptB[jb][rg] = (short)(__float_as_uint(pb) >> 16);
            }
        }
        lA = lA * alA + lpA;
        lB = lB * alB + lpB;

#pragma unroll
        for (int db = 0; db < 4; db++) {
            OaA[db][0] *= alA; OaA[db][1] *= alA; OaA[db][2] *= alA; OaA[db][3] *= alA;
            OaB[db][0] *= alB; OaB[db][1] *= alB; OaB[db][2] *= alB; OaB[db][3] *= alB;
        }

        // O^T += V^T · P^T; V-frags (b64) read once per (db,jb)
#pragma unroll
        for (int db = 0; db < 4; db++) {
            const u16* vr = VtC + (db * 16 + col) * 128;
#pragma unroll
            for (int jb = 0; jb < 8; jb++) {
                int ch = jb * 2 + (quad >> 1);
                short4v va = *(const short4v*)(vr + ((ch ^ c7) * 8) + (quad & 1) * 4);
                OaA[db] = MFMA_K16(va, ptA[jb], OaA[db]);
                OaB[db] = MFMA_K16(va, ptB[jb], OaB[db]);
            }
        }
        __syncthreads();
    }
#undef STAGE

    // deferred l reduction across quads (m already consistent)
    lA += __shfl_xor(lA, 16);
    lB += __shfl_xor(lB, 16);
    lA += __shfl_xor(lA, 32);
    lB += __shfl_xor(lB, 32);

    // epilogue: attnT bf16 [n][q][c], c = h*64 + db*16 + quad*4 + rg -> packed 8B stores
    float rlA = 1.0f / lA, rlB = 1.0f / lB;
    u16* abA = attnT + ((size_t)(nh >> 2) * HW + q0 + w * 32 + col) * 256 + (nh & 3) * 64 + quad * 4;
    u16* abB = abA + 16 * 256;
#pragma unroll
    for (int db = 0; db < 4; db++) {
        uint2 oA, oB;
        oA.x = (u32)f2b(OaA[db][0] * rlA) | ((u32)f2b(OaA[db][1] * rlA) << 16);
        oA.y = (u32)f2b(OaA[db][2] * rlA) | ((u32)f2b(OaA[db][3] * rlA) << 16);
        oB.x = (u32)f2b(OaB[db][0] * rlB) | ((u32)f2b(OaB[db][1] * rlB) << 16);
        oB.y = (u32)f2b(OaB[db][2] * rlB) | ((u32)f2b(OaB[db][3] * rlB) << 16);
        *(uint2*)(abA + db * 16) = oA;
        *(uint2*)(abB + db * 16) = oB;
    }
}

// ---------------- Proj MFMA GEMM + bias + residual + mask ----------------
__global__ __launch_bounds__(256) void proj_mfma(const u16* __restrict__ attnT, const u16* __restrict__ Wpb,
                                                 const float* __restrict__ bp, const float* __restrict__ x,
                                                 const float* __restrict__ mask, float* __restrict__ out) {
    __shared__ u16 Xs[64 * 256];
    int t = threadIdx.x;
    int w = t >> 6, lane = t & 63;
    int col = lane & 15, quad = lane >> 4;
    int p0 = blockIdx.x * 64;
    int o0 = blockIdx.y * 64;
    int n = blockIdx.z;

#pragma unroll
    for (int j = 0; j < 8; j++) {
        int rl = j * 2 + (lane >> 5);
        int row = w * 16 + rl;
        int slot = (lane & 31) ^ (rl & 7);
        GLDS(attnT + ((size_t)n * HW + p0 + row) * 256 + slot * 8, Xs + (w * 16 + j * 2) * 256);
    }

    const u16* wrow = Wpb + (size_t)(o0 + w * 16 + col) * 256 + quad * 8;
    short8 A[8];
#pragma unroll
    for (int ks = 0; ks < 8; ks++) A[ks] = *(const short8*)(wrow + ks * 32);

    __syncthreads();

    f32x4 C[4];
#pragma unroll
    for (int pb = 0; pb < 4; pb++) C[pb] = (f32x4){0.f, 0.f, 0.f, 0.f};
    int c7 = col & 7;
#pragma unroll
    for (int pb = 0; pb < 4; pb++) {
        const u16* xr = Xs + (pb * 16 + col) * 256;
#pragma unroll
        for (int ks = 0; ks < 8; ks++) {
            int slot = (ks * 4 + quad) ^ c7;
            short8 Bf = *(const short8*)(xr + slot * 8);
            C[pb] = MFMA_K32(A[ks], Bf, C[pb]);
        }
    }

#pragma unroll
    for (int rg = 0; rg < 4; rg++) {
        int o = o0 + w * 16 + quad * 4 + rg;
        float bias = bp[o];
        const float* xb = x + ((size_t)n * 256 + o) * HW + p0 + col;
        float* ob = out + ((size_t)n * 256 + o) * HW + p0 + col;
        const float* mb = mask + (size_t)n * HW + p0 + col;
#pragma unroll
        for (int pb = 0; pb < 4; pb++) {
            float mv = mb[pb * 16];
            ob[pb * 16] = (xb[pb * 16] + C[pb][rg] + bias) * mv;
        }
    }
}

// ---------------- mask passthrough ----------------
__global__ __launch_bounds__(256) void mask_copy(const float* __restrict__ mask, float* __restrict__ out) {
    int i = blockIdx.x * 256 + threadIdx.x;
    out[i] = mask[i];
}

extern "C" void kernel_launch(void* const* d_in, const int* in_sizes, int n_in,
                              void* d_out, int out_size, void* d_ws, size_t ws_size,
                              hipStream_t stream) {
    const float* x = (const float*)d_in[0];
    const float* mask = (const float*)d_in[1];
    const float* norm_w = (const float*)d_in[2];
    const float* norm_b = (const float*)d_in[3];
    const float* qkv_w = (const float*)d_in[4];
    const float* qkv_b = (const float*)d_in[5];
    const float* proj_w = (const float*)d_in[6];
    const float* proj_b = (const float*)d_in[7];
    float* out = (float*)d_out;

    float* ws = (float*)d_ws;
    float* stats = ws;                    // 64 f32
    float* pstats = ws + 64;              // 1024 f32
    u16* xt = (u16*)(ws + 2048);          // 4,194,304 u16
    u16* Qw = xt + 4194304;
    u16* Kw = Qw + 4194304;
    u16* Vw = Kw + 4194304;
    u16* attnT = Vw + 4194304;
    u16* Wqb = attnT + 4194304;           // 196,608 u16
    u16* Wpb = Wqb + 196608;              // 65,536 u16

    gn_partial<<<512, 256, 0, stream>>>(x, pstats);
    gn_final<<<1, 64, 0, stream>>>(pstats, stats);
    wconv<<<192, 256, 0, stream>>>(qkv_w, Wqb, 256);   // 768*256/4 threads
    wconv<<<64, 256, 0, stream>>>(proj_w, Wpb, 0);     // 256*256/4 threads
    gn_apply_t<<<dim3(64, 4, 4), 256, 0, stream>>>(x, norm_w, norm_b, stats, xt);
    qkv_mfma<<<dim3(64, 12, 4), 256, 0, stream>>>(xt, Wqb, qkv_b, Qw, Kw, Vw);
    flash_mfma<<<dim3(32, 16), 256, 0, stream>>>(Qw, Kw, Vw, attnT);
    proj_mfma<<<dim3(64, 4, 4), 256, 0, stream>>>(attnT, Wpb, proj_b, x, mask, out);
    mask_copy<<<64, 256, 0, stream>>>(mask, out + 4194304);
}